// Round 1
// baseline (1317.955 us; speedup 1.0000x reference)
//
#include <hip/hip_runtime.h>

#define NN 50000
#define D 256
#define NQ 128
#define PG 256
#define NE 32768
#define ME 64
#define CHUNK 8192
#define NCHUNKS 4

__device__ __forceinline__ float dot4f(float4 a, float4 b){
  return a.x*b.x + a.y*b.y + a.z*b.z + a.w*b.w;
}
__device__ __forceinline__ unsigned fenc(float f){
  unsigned b = __float_as_uint(f);
  return (b & 0x80000000u) ? ~b : (b | 0x80000000u);
}
__device__ __forceinline__ float fdec(unsigned u){
  unsigned b = (u & 0x80000000u) ? (u & 0x7fffffffu) : ~u;
  return __uint_as_float(b);
}

// ---------------- generic fp32 tiled GEMM: C = A(MxK) @ B(KxN), row-major ----
// tile 64x64, 256 threads, 4x4 per thread, K-chunk 16. EPI=1: bias + leaky_relu.
template<int EPI>
__global__ __launch_bounds__(256) void gemm64(const float* __restrict__ A, int lda,
                                              const float* __restrict__ B, int ldb,
                                              float* __restrict__ C, int ldc,
                                              int Mrows, int Kdim,
                                              const float* __restrict__ bias)
{
  __shared__ float As[16][68];
  __shared__ float Bs[16][68];
  const int tid = threadIdx.x;
  const int rb = blockIdx.x * 64, cb = blockIdx.y * 64;
  const int ty = tid >> 4, tx = tid & 15;
  const int am = tid >> 2, ak = (tid & 3) << 2;   // A: 64 rows x 16 k, float4 along k
  const int bk = tid >> 4, bn = (tid & 15) << 2;  // B: 16 k x 64 n, float4 along n
  float acc[4][4] = {};
  for (int k0 = 0; k0 < Kdim; k0 += 16) {
    float4 av = make_float4(0.f,0.f,0.f,0.f);
    int arow = rb + am;
    if (arow < Mrows) av = *(const float4*)(A + (size_t)arow*lda + k0 + ak);
    As[ak+0][am]=av.x; As[ak+1][am]=av.y; As[ak+2][am]=av.z; As[ak+3][am]=av.w;
    float4 bv = *(const float4*)(B + (size_t)(k0+bk)*ldb + cb + bn);
    Bs[bk][bn+0]=bv.x; Bs[bk][bn+1]=bv.y; Bs[bk][bn+2]=bv.z; Bs[bk][bn+3]=bv.w;
    __syncthreads();
#pragma unroll
    for (int kk=0; kk<16; ++kk) {
      float a0=As[kk][ty*4+0],a1=As[kk][ty*4+1],a2=As[kk][ty*4+2],a3=As[kk][ty*4+3];
      float b0=Bs[kk][tx*4+0],b1=Bs[kk][tx*4+1],b2=Bs[kk][tx*4+2],b3=Bs[kk][tx*4+3];
      acc[0][0]+=a0*b0; acc[0][1]+=a0*b1; acc[0][2]+=a0*b2; acc[0][3]+=a0*b3;
      acc[1][0]+=a1*b0; acc[1][1]+=a1*b1; acc[1][2]+=a1*b2; acc[1][3]+=a1*b3;
      acc[2][0]+=a2*b0; acc[2][1]+=a2*b1; acc[2][2]+=a2*b2; acc[2][3]+=a2*b3;
      acc[3][0]+=a3*b0; acc[3][1]+=a3*b1; acc[3][2]+=a3*b2; acc[3][3]+=a3*b3;
    }
    __syncthreads();
  }
#pragma unroll
  for (int i=0;i<4;++i){
    int row = rb + ty*4 + i;
    if (row < Mrows){
#pragma unroll
      for (int j=0;j<4;++j){
        float v = acc[i][j];
        int col = cb + tx*4 + j;
        if (EPI==1){ v += bias[col]; v = v > 0.f ? v : 0.01f*v; }
        C[(size_t)row*ldc + col] = v;
      }
    }
  }
}

// ---------------- M = Wq^T @ Wk  (1024x1024, fp64 accumulate) ---------------
__global__ __launch_bounds__(256) void gemm_tn(const float* __restrict__ A,
                                               const float* __restrict__ B,
                                               float* __restrict__ C)
{
  __shared__ float As[16][68];
  __shared__ float Bs[16][68];
  const int tid = threadIdx.x;
  const int rb = blockIdx.x * 64, cb = blockIdx.y * 64;
  const int ty = tid >> 4, tx = tid & 15;
  const int aj = tid >> 4, akk = (tid & 15) << 2;
  double acc[4][4] = {};
  for (int j0 = 0; j0 < 1024; j0 += 16) {
    float4 av = *(const float4*)(A + (size_t)(j0+aj)*1024 + rb + akk);
    As[aj][akk+0]=av.x; As[aj][akk+1]=av.y; As[aj][akk+2]=av.z; As[aj][akk+3]=av.w;
    float4 bv = *(const float4*)(B + (size_t)(j0+aj)*1024 + cb + akk);
    Bs[aj][akk+0]=bv.x; Bs[aj][akk+1]=bv.y; Bs[aj][akk+2]=bv.z; Bs[aj][akk+3]=bv.w;
    __syncthreads();
#pragma unroll
    for (int jj=0; jj<16; ++jj){
      float a0=As[jj][ty*4+0],a1=As[jj][ty*4+1],a2=As[jj][ty*4+2],a3=As[jj][ty*4+3];
      float b0=Bs[jj][tx*4+0],b1=Bs[jj][tx*4+1],b2=Bs[jj][tx*4+2],b3=Bs[jj][tx*4+3];
      acc[0][0]+=(double)a0*b0; acc[0][1]+=(double)a0*b1; acc[0][2]+=(double)a0*b2; acc[0][3]+=(double)a0*b3;
      acc[1][0]+=(double)a1*b0; acc[1][1]+=(double)a1*b1; acc[1][2]+=(double)a1*b2; acc[1][3]+=(double)a1*b3;
      acc[2][0]+=(double)a2*b0; acc[2][1]+=(double)a2*b1; acc[2][2]+=(double)a2*b2; acc[2][3]+=(double)a2*b3;
      acc[3][0]+=(double)a3*b0; acc[3][1]+=(double)a3*b1; acc[3][2]+=(double)a3*b2; acc[3][3]+=(double)a3*b3;
    }
    __syncthreads();
  }
#pragma unroll
  for (int i=0;i<4;++i)
#pragma unroll
    for (int j=0;j<4;++j)
      C[(size_t)(rb+ty*4+i)*1024 + cb+tx*4+j] = (float)acc[i][j];
}

// ---------------- build Wcat (256 x 768): cols [a1 | a2 | a3] ----------------
__global__ void build_wcat(const float* __restrict__ M, float* __restrict__ Wcat)
{
  int idx = blockIdx.x*256 + threadIdx.x;
  if (idx >= 256*768) return;
  int k = idx / 768, j = idx % 768;
  float v;
  if (j < 256)       v = M[(size_t)j*1024 + 256 + k];          // a1: M_hr^T
  else if (j < 512)  v = M[(size_t)(256+k)*1024 + (j-256)];    // a2: M_rh
  else               v = M[(size_t)(256+(j-512))*1024 + 256+k];// a3: M_rr^T
  Wcat[idx] = v;
}

__global__ void build_wlt(const float* __restrict__ Wl, float* __restrict__ WlT)
{
  int idx = blockIdx.x*256 + threadIdx.x;
  if (idx >= 256*256) return;
  int k = idx / 256, j = idx % 256;
  WlT[idx] = Wl[(size_t)j*256 + k];
}

// ---------------- per-query tables t1,t2,w (128x256) and c (128) ------------
__global__ __launch_bounds__(256) void query_tables(const float* __restrict__ M,
    const float* __restrict__ qst, const float* __restrict__ qr,
    float* __restrict__ qt1, float* __restrict__ qt2, float* __restrict__ qw,
    float* __restrict__ qc)
{
  int q = blockIdx.x, t = threadIdx.x;
  __shared__ float g[512];
  __shared__ float red[256];
  g[t]       = qst[(size_t)q*256 + t];
  g[t + 256] = qr [(size_t)q*256 + t];
  __syncthreads();
  float s1=0.f, s2=0.f, sw=0.f, v1=0.f, v2=0.f;
  for (int k=0;k<512;++k){
    float gk = g[k];
    s1 += M[(size_t)t*1024 + 512 + k] * gk;                 // t1 = M_hg g
    s2 += M[(size_t)(512+k)*1024 + t] * gk;                 // t2 = M_gh^T g
    sw += (M[(size_t)(256+t)*1024 + 512 + k] +
           M[(size_t)(512+k)*1024 + 256 + t]) * gk;         // w = M_rg g + M_gr^T g
    v1 += M[(size_t)(512+k)*1024 + 512 + t] * gk;           // v(k2=t)
    v2 += M[(size_t)(512+k)*1024 + 768 + t] * gk;           // v(k2=t+256)
  }
  qt1[(size_t)q*256+t]=s1; qt2[(size_t)q*256+t]=s2; qw[(size_t)q*256+t]=sw;
  red[t] = v1*g[t] + v2*g[t+256];
  __syncthreads();
  for (int s=128; s>0; s>>=1){
    if (t < s) red[t] += red[t+s];
    __syncthreads();
  }
  if (t==0) qc[q] = red[0];
}

// ---------------- per-edge logits (one wave per edge) -----------------------
__global__ __launch_bounds__(256) void logits_k(const int* __restrict__ edges, int ebase,
    const float* __restrict__ H, const float* __restrict__ U, const float* __restrict__ Rel,
    const float* __restrict__ Grelc,
    const float* __restrict__ qt1, const float* __restrict__ qt2,
    const float* __restrict__ qw, const float* __restrict__ qc,
    float* __restrict__ logits)
{
  int lane = threadIdx.x & 63;
  int el = blockIdx.x*4 + (threadIdx.x >> 6);   // edge index within chunk
  int e  = ebase + el;
  int q   = edges[(size_t)e*8 + 0];
  int src = edges[(size_t)e*8 + 6];
  int dst = edges[(size_t)e*8 + 7];
  const float4* hs = (const float4*)(H   + (size_t)src*256);
  const float4* hd = (const float4*)(H   + (size_t)dst*256);
  const float4* us = (const float4*)(U   + (size_t)src*256);
  const float4* rl = (const float4*)(Rel + (size_t)e*256);
  const float4* g1 = (const float4*)(Grelc + (size_t)el*768);
  const float4* g2 = g1 + 64;
  const float4* g3 = g1 + 128;
  const float4* t1 = (const float4*)(qt1 + (size_t)q*256);
  const float4* t2 = (const float4*)(qt2 + (size_t)q*256);
  const float4* w4 = (const float4*)(qw  + (size_t)q*256);

  float4 a, b, c, d;
  float s = 0.f;
  a = hd[lane]; b = us[lane]; c = g2[lane]; d = t2[lane];
  s += a.x*(b.x+c.x+d.x) + a.y*(b.y+c.y+d.y) + a.z*(b.z+c.z+d.z) + a.w*(b.w+c.w+d.w);
  a = hs[lane]; b = g1[lane]; c = t1[lane];
  s += a.x*(b.x+c.x) + a.y*(b.y+c.y) + a.z*(b.z+c.z) + a.w*(b.w+c.w);
  a = rl[lane]; b = g3[lane]; c = w4[lane];
  s += a.x*(b.x+c.x) + a.y*(b.y+c.y) + a.z*(b.z+c.z) + a.w*(b.w+c.w);
#pragma unroll
  for (int off=32; off>0; off>>=1) s += __shfl_down(s, off);
  if (lane==0) logits[e] = s + qc[q];
}

// ---------------- segmented softmax over src-node segments ------------------
__global__ void segmax_k(const int* __restrict__ edges, const float* __restrict__ logits,
                         unsigned* __restrict__ menc, int nE)
{
  int e = blockIdx.x*256 + threadIdx.x; if (e >= nE) return;
  atomicMax(menc + edges[(size_t)e*8+6], fenc(logits[e]));
}
__global__ void segexp_k(const int* __restrict__ edges, const float* __restrict__ logits,
                         const unsigned* __restrict__ menc, float* __restrict__ ebuf,
                         float* __restrict__ ssum, int nE)
{
  int e = blockIdx.x*256 + threadIdx.x; if (e >= nE) return;
  int s = edges[(size_t)e*8+6];
  float ex = expf(logits[e] - fdec(menc[s]));
  ebuf[e] = ex;
  atomicAdd(ssum + s, ex);
}
template<int TGT>
__global__ void segsoft_k(const int* __restrict__ edges, const float* __restrict__ ebuf,
                          const float* __restrict__ ssum, float* __restrict__ soft,
                          const float* __restrict__ score, float* __restrict__ target, int nE)
{
  int e = blockIdx.x*256 + threadIdx.x; if (e >= nE) return;
  int s = edges[(size_t)e*8+6];
  float so = ebuf[e] / ssum[s];
  soft[e] = so;
  if (TGT) target[e] = so * score[s];
}

// ---------------- per-query top-64 (bitonic, matches top_k tie order) -------
__global__ __launch_bounds__(256) void topk_k(const float* __restrict__ target,
    const float* __restrict__ soft, const int* __restrict__ edges1,
    float* __restrict__ out0, float* __restrict__ out2, float* __restrict__ out3,
    int* __restrict__ p_src, int* __restrict__ p_dst, float* __restrict__ p_w)
{
  int qb = blockIdx.x, t = threadIdx.x;
  __shared__ float v[256];
  __shared__ int   ix[256];
  v[t] = target[(size_t)qb*256 + t];
  ix[t] = t;
  __syncthreads();
  for (int k=2; k<=256; k<<=1){
    for (int j=k>>1; j>0; j>>=1){
      int ixj = t ^ j;
      if (ixj > t){
        float va=v[t], vb=v[ixj]; int ia=ix[t], ib=ix[ixj];
        bool dir  = ((t & k) == 0);
        bool l_ab = (va > vb) || (va == vb && ia < ib);   // a ranks before b
        bool sw   = dir ? (!l_ab) : l_ab;
        if (sw){ v[t]=vb; v[ixj]=va; ix[t]=ib; ix[ixj]=ia; }
      }
      __syncthreads();
    }
  }
  if (t < 64){
    int oi = qb*256 + ix[t];
    int o  = qb*64 + t;
    out3[o] = (float)oi;
#pragma unroll
    for (int c2=0;c2<8;++c2) out2[(size_t)o*8 + c2] = (float)edges1[(size_t)oi*8 + c2];
    int s_ = edges1[(size_t)oi*8+6], d_ = edges1[(size_t)oi*8+7];
    p_src[o] = s_; p_dst[o] = d_; p_w[o] = soft[oi];
    atomicAdd(out0 + d_, v[t]);   // pruned_soft * pruned_src_score
  }
}

// ---------------- repr update helpers ---------------------------------------
__global__ void flag_k(const int* __restrict__ arr, int stride, int n,
                       unsigned char* __restrict__ flg)
{
  int i = blockIdx.x*256 + threadIdx.x;
  if (i < n) flg[arr[(size_t)i*stride]] = 1;
}
__global__ __launch_bounds__(256) void diag_k(const unsigned char* __restrict__ flg,
    const float* __restrict__ Hin, float* __restrict__ Hout)
{
  int gid = blockIdx.x*256 + threadIdx.x;   // NN*64 threads
  int n = gid >> 6, c = gid & 63;
  float fac = flg[n] ? 0.2f : 1.0f;
  float4 vv = ((const float4*)(Hin + (size_t)n*256))[c];
  vv.x*=fac; vv.y*=fac; vv.z*=fac; vv.w*=fac;
  ((float4*)(Hout + (size_t)n*256))[c] = vv;
}
__global__ __launch_bounds__(256) void agg_k(const int* __restrict__ srcarr,
    const int* __restrict__ dstarr, int stride, const float* __restrict__ w,
    const float* __restrict__ Hin, float* __restrict__ Hout, int nE)
{
  int lane = threadIdx.x & 63;
  int e = blockIdx.x*4 + (threadIdx.x >> 6);
  if (e >= nE) return;
  int s = srcarr[(size_t)e*stride];
  int d = dstarr[(size_t)e*stride];
  float f = 0.8f * w[e];
  float4 vv = ((const float4*)(Hin + (size_t)d*256))[lane];
  float* o = Hout + (size_t)s*256 + lane*4;
  atomicAdd(o+0, f*vv.x); atomicAdd(o+1, f*vv.y);
  atomicAdd(o+2, f*vv.z); atomicAdd(o+3, f*vv.w);
}

// ---------------- host launch ------------------------------------------------
extern "C" void kernel_launch(void* const* d_in, const int* in_sizes, int n_in,
                              void* d_out, int out_size, void* d_ws, size_t ws_size,
                              hipStream_t stream)
{
  const float* score = (const float*)d_in[0];
  const float* H0    = (const float*)d_in[1];
  const int*   edges0= (const int*)d_in[2];
  const int*   edges1= (const int*)d_in[3];
  const float* rel0  = (const float*)d_in[4];
  const float* rel1  = (const float*)d_in[5];
  const float* qst   = (const float*)d_in[6];
  const float* qr    = (const float*)d_in[7];
  const float* Wq    = (const float*)d_in[8];
  const float* Wk    = (const float*)d_in[9];
  const float* Wl    = (const float*)d_in[10];
  const float* bl    = (const float*)d_in[11];
  (void)in_sizes; (void)n_in; (void)out_size; (void)ws_size;

  float* out0 = (float*)d_out;                 // updated_node_score (50000)
  float* out1 = out0 + NN;                     // node_repr (50000*256)
  float* out2 = out1 + (size_t)NN*D;           // pruned_edges (8192*8)
  float* out3 = out2 + (size_t)NQ*ME*8;        // orig_indices (8192)

  float* ws     = (float*)d_ws;
  float* Mbuf   = ws;                          // 1,048,576
  float* Wcat   = ws + 1048576;                // 196,608
  float* WlT    = ws + 1245184;                // 65,536
  float* qt1    = ws + 1310720;                // 32,768
  float* qt2    = ws + 1343488;
  float* qw     = ws + 1376256;
  float* qc     = ws + 1409024;                // 128
  float* logits = ws + 1409152;                // 32,768
  float* ebuf   = ws + 1441920;
  float* soft   = ws + 1474688;
  float* target = ws + 1507456;
  unsigned* menc= (unsigned*)(ws + 1540224);   // 50,000
  float* ssum   = ws + 1590224;                // 50,000
  int* p_src    = (int*)(ws + 1640224);        // 8,192
  int* p_dst    = (int*)(ws + 1648416);
  float* p_w    = ws + 1656608;
  unsigned char* is_src = (unsigned char*)(ws + 1664800); // 50,000 B (12,512 f)
  float* U      = ws + 1677312;                // 12,800,000  (also reused as Hpre)
  float* Hnew   = ws + 14477312;               // 12,800,000
  float* Grelc  = ws + 27277312;               // 8192*768 = 6,291,456
  float* Hpre   = U;                           // alias: U dead before Hpre written

  // init
  hipMemsetAsync(out0, 0, (size_t)NN*4, stream);
  hipMemsetAsync(menc, 0, (size_t)NN*4, stream);   // fenc(x) > 0 for all finite x
  hipMemsetAsync(ssum, 0, (size_t)NN*4, stream);
  hipMemsetAsync(is_src, 0, (size_t)NN, stream);

  // precompute M = Wq^T Wk, Wcat, WlT, query tables
  gemm_tn<<<dim3(16,16), 256, 0, stream>>>(Wq, Wk, Mbuf);
  build_wcat<<<768, 256, 0, stream>>>(Mbuf, Wcat);
  build_wlt<<<256, 256, 0, stream>>>(Wl, WlT);
  query_tables<<<NQ, 256, 0, stream>>>(Mbuf, qst, qr, qt1, qt2, qw, qc);

  // ---- call 1: edges1 / rel1 / H0 ----
  gemm64<0><<<dim3(782,4), 256, 0, stream>>>(H0, 256, Mbuf, 1024, U, 256, NN, 256, nullptr);
  for (int c = 0; c < NCHUNKS; ++c){
    gemm64<0><<<dim3(CHUNK/64, 768/64), 256, 0, stream>>>(
        rel1 + (size_t)c*CHUNK*256, 256, Wcat, 768, Grelc, 768, CHUNK, 256, nullptr);
    logits_k<<<CHUNK/4, 256, 0, stream>>>(edges1, c*CHUNK, H0, U, rel1, Grelc,
                                          qt1, qt2, qw, qc, logits);
  }
  segmax_k<<<NE/256, 256, 0, stream>>>(edges1, logits, menc, NE);
  segexp_k<<<NE/256, 256, 0, stream>>>(edges1, logits, menc, ebuf, ssum, NE);
  segsoft_k<1><<<NE/256, 256, 0, stream>>>(edges1, ebuf, ssum, soft, score, target, NE);

  topk_k<<<NQ, 256, 0, stream>>>(target, soft, edges1, out0, out2, out3, p_src, p_dst, p_w);

  flag_k<<<(NQ*ME+255)/256, 256, 0, stream>>>(p_src, 1, NQ*ME, is_src);
  diag_k<<<NN*64/256, 256, 0, stream>>>(is_src, H0, Hnew);
  agg_k<<<(NQ*ME)/4, 256, 0, stream>>>(p_src, p_dst, 1, p_w, H0, Hnew, NQ*ME);

  // re-init for call 2
  hipMemsetAsync(menc, 0, (size_t)NN*4, stream);
  hipMemsetAsync(ssum, 0, (size_t)NN*4, stream);
  hipMemsetAsync(is_src, 0, (size_t)NN, stream);

  // ---- call 2: edges0 / rel0 / Hnew ----
  gemm64<0><<<dim3(782,4), 256, 0, stream>>>(Hnew, 256, Mbuf, 1024, U, 256, NN, 256, nullptr);
  for (int c = 0; c < NCHUNKS; ++c){
    gemm64<0><<<dim3(CHUNK/64, 768/64), 256, 0, stream>>>(
        rel0 + (size_t)c*CHUNK*256, 256, Wcat, 768, Grelc, 768, CHUNK, 256, nullptr);
    logits_k<<<CHUNK/4, 256, 0, stream>>>(edges0, c*CHUNK, Hnew, U, rel0, Grelc,
                                          qt1, qt2, qw, qc, logits);
  }
  segmax_k<<<NE/256, 256, 0, stream>>>(edges0, logits, menc, NE);
  segexp_k<<<NE/256, 256, 0, stream>>>(edges0, logits, menc, ebuf, ssum, NE);
  segsoft_k<0><<<NE/256, 256, 0, stream>>>(edges0, ebuf, ssum, soft, nullptr, nullptr, NE);

  flag_k<<<NE/256, 256, 0, stream>>>(edges0 + 6, 8, NE, is_src);
  diag_k<<<NN*64/256, 256, 0, stream>>>(is_src, Hnew, Hpre);
  agg_k<<<NE/4, 256, 0, stream>>>(edges0 + 6, edges0 + 7, 8, soft, Hnew, Hpre, NE);

  // final: out1 = leaky_relu(Hpre @ Wl^T + bl)
  gemm64<1><<<dim3(782,4), 256, 0, stream>>>(Hpre, 256, WlT, 256, out1, 256, NN, 256, bl);
}

// Round 2
// 1224.999 us; speedup vs baseline: 1.0759x; 1.0759x over previous
//
#include <hip/hip_runtime.h>

#define NN 50000
#define D 256
#define NQ 128
#define PG 256
#define NE 32768
#define ME 64
#define CHUNK 8192
#define NCHUNKS 4
#define BCAP 32

__device__ __forceinline__ unsigned fenc(float f){
  unsigned b = __float_as_uint(f);
  return (b & 0x80000000u) ? ~b : (b | 0x80000000u);
}
__device__ __forceinline__ float fdec(unsigned u){
  unsigned b = (u & 0x80000000u) ? (u & 0x7fffffffu) : ~u;
  return __uint_as_float(b);
}

// ---------------- fp32 GEMM: C = A(MxK) @ B(KxN), 128x128 tile, 8x8/thread --
template<int EPI>
__global__ __launch_bounds__(256) void gemm128(const float* __restrict__ A, int lda,
                                               const float* __restrict__ B, int ldb,
                                               float* __restrict__ C, int ldc,
                                               int Mrows, int Kdim,
                                               const float* __restrict__ bias)
{
  __shared__ float As[16][132];   // k-major, padded
  __shared__ float Bs[16][128];
  const int tid = threadIdx.x;
  const int rb = blockIdx.x * 128, cb = blockIdx.y * 128;
  const int tx = tid & 15, ty = tid >> 4;        // C: rows ty*8.., cols tx*8..
  const int a_r = tid >> 1, a_k = (tid & 1) * 8; // A stage: 128 rows x 16 k
  const int b_k = tid >> 4, b_c = (tid & 15) * 8;// B stage: 16 k x 128 n
  float acc[8][8] = {};
  for (int k0 = 0; k0 < Kdim; k0 += 16) {
    float4 av0 = make_float4(0.f,0.f,0.f,0.f), av1 = av0;
    int ar = rb + a_r;
    if (ar < Mrows) {
      av0 = *(const float4*)(A + (size_t)ar*lda + k0 + a_k);
      av1 = *(const float4*)(A + (size_t)ar*lda + k0 + a_k + 4);
    }
    float4 bv0 = *(const float4*)(B + (size_t)(k0+b_k)*ldb + cb + b_c);
    float4 bv1 = *(const float4*)(B + (size_t)(k0+b_k)*ldb + cb + b_c + 4);
    __syncthreads();   // previous iter's LDS reads done
    As[a_k+0][a_r]=av0.x; As[a_k+1][a_r]=av0.y; As[a_k+2][a_r]=av0.z; As[a_k+3][a_r]=av0.w;
    As[a_k+4][a_r]=av1.x; As[a_k+5][a_r]=av1.y; As[a_k+6][a_r]=av1.z; As[a_k+7][a_r]=av1.w;
    *(float4*)&Bs[b_k][b_c]   = bv0;
    *(float4*)&Bs[b_k][b_c+4] = bv1;
    __syncthreads();
#pragma unroll
    for (int kk=0; kk<16; ++kk){
      float a[8], b[8];
      *(float4*)&a[0] = *(const float4*)&As[kk][ty*8];
      *(float4*)&a[4] = *(const float4*)&As[kk][ty*8+4];
      *(float4*)&b[0] = *(const float4*)&Bs[kk][tx*8];
      *(float4*)&b[4] = *(const float4*)&Bs[kk][tx*8+4];
#pragma unroll
      for (int i=0;i<8;++i)
#pragma unroll
        for (int j=0;j<8;++j) acc[i][j] += a[i]*b[j];
    }
  }
#pragma unroll
  for (int i=0;i<8;++i){
    int row = rb + ty*8 + i;
    if (row < Mrows){
#pragma unroll
      for (int j=0;j<8;++j){
        float v = acc[i][j];
        int col = cb + tx*8 + j;
        if (EPI==1){ v += bias[col]; v = v > 0.f ? v : 0.01f*v; }
        C[(size_t)row*ldc + col] = v;
      }
    }
  }
}

// ------- M = Wq^T @ Wk (1024x1024), fp64 accumulate, split-K x4 -------------
__global__ __launch_bounds__(256) void gemm_tn_split(const float* __restrict__ A,
                                                     const float* __restrict__ B,
                                                     double* __restrict__ Cpart)
{
  __shared__ float As[16][68];
  __shared__ float Bs[16][68];
  const int tid = threadIdx.x;
  const int rb = blockIdx.x * 64, cb = blockIdx.y * 64;
  const int z  = blockIdx.z;                 // K-split index
  const int ty = tid >> 4, tx = tid & 15;
  const int aj = tid >> 4, akk = (tid & 15) << 2;
  double acc[4][4] = {};
  const int jbeg = z * 256, jend = jbeg + 256;
  for (int j0 = jbeg; j0 < jend; j0 += 16) {
    float4 av = *(const float4*)(A + (size_t)(j0+aj)*1024 + rb + akk);
    As[aj][akk+0]=av.x; As[aj][akk+1]=av.y; As[aj][akk+2]=av.z; As[aj][akk+3]=av.w;
    float4 bv = *(const float4*)(B + (size_t)(j0+aj)*1024 + cb + akk);
    Bs[aj][akk+0]=bv.x; Bs[aj][akk+1]=bv.y; Bs[aj][akk+2]=bv.z; Bs[aj][akk+3]=bv.w;
    __syncthreads();
#pragma unroll
    for (int jj=0; jj<16; ++jj){
      float a0=As[jj][ty*4+0],a1=As[jj][ty*4+1],a2=As[jj][ty*4+2],a3=As[jj][ty*4+3];
      float b0=Bs[jj][tx*4+0],b1=Bs[jj][tx*4+1],b2=Bs[jj][tx*4+2],b3=Bs[jj][tx*4+3];
      acc[0][0]+=(double)a0*b0; acc[0][1]+=(double)a0*b1; acc[0][2]+=(double)a0*b2; acc[0][3]+=(double)a0*b3;
      acc[1][0]+=(double)a1*b0; acc[1][1]+=(double)a1*b1; acc[1][2]+=(double)a1*b2; acc[1][3]+=(double)a1*b3;
      acc[2][0]+=(double)a2*b0; acc[2][1]+=(double)a2*b1; acc[2][2]+=(double)a2*b2; acc[2][3]+=(double)a2*b3;
      acc[3][0]+=(double)a3*b0; acc[3][1]+=(double)a3*b1; acc[3][2]+=(double)a3*b2; acc[3][3]+=(double)a3*b3;
    }
    __syncthreads();
  }
  double* Cz = Cpart + (size_t)z * 1048576;
#pragma unroll
  for (int i=0;i<4;++i)
#pragma unroll
    for (int j=0;j<4;++j)
      Cz[(size_t)(rb+ty*4+i)*1024 + cb+tx*4+j] = acc[i][j];
}

__global__ void reduce_m(const double* __restrict__ P, float* __restrict__ Mout)
{
  int i = blockIdx.x*256 + threadIdx.x;
  Mout[i] = (float)(P[i] + P[i+1048576] + P[i+2097152] + P[i+3145728]);
}

// ---------------- build Wcat (256 x 768): cols [a1 | a2 | a3] ----------------
__global__ void build_wcat(const float* __restrict__ M, float* __restrict__ Wcat)
{
  int idx = blockIdx.x*256 + threadIdx.x;
  if (idx >= 256*768) return;
  int k = idx / 768, j = idx % 768;
  float v;
  if (j < 256)       v = M[(size_t)j*1024 + 256 + k];          // a1: M_hr^T
  else if (j < 512)  v = M[(size_t)(256+k)*1024 + (j-256)];    // a2: M_rh
  else               v = M[(size_t)(256+(j-512))*1024 + 256+k];// a3: M_rr^T
  Wcat[idx] = v;
}

__global__ void build_wlt(const float* __restrict__ Wl, float* __restrict__ WlT)
{
  int idx = blockIdx.x*256 + threadIdx.x;
  if (idx >= 256*256) return;
  int k = idx / 256, j = idx % 256;
  WlT[idx] = Wl[(size_t)j*256 + k];
}

// ---------------- per-query tables t1,t2,w (128x256) and c (128) ------------
__global__ __launch_bounds__(256) void query_tables(const float* __restrict__ M,
    const float* __restrict__ qst, const float* __restrict__ qr,
    float* __restrict__ qt1, float* __restrict__ qt2, float* __restrict__ qw,
    float* __restrict__ qc)
{
  int q = blockIdx.x, t = threadIdx.x;
  __shared__ float g[512];
  __shared__ float red[256];
  g[t]       = qst[(size_t)q*256 + t];
  g[t + 256] = qr [(size_t)q*256 + t];
  __syncthreads();
  float s1=0.f, s2=0.f, sw=0.f, v1=0.f, v2=0.f;
  for (int k=0;k<512;++k){
    float gk = g[k];
    s1 += M[(size_t)t*1024 + 512 + k] * gk;                 // t1 = M_hg g
    s2 += M[(size_t)(512+k)*1024 + t] * gk;                 // t2 = M_gh^T g
    sw += (M[(size_t)(256+t)*1024 + 512 + k] +
           M[(size_t)(512+k)*1024 + 256 + t]) * gk;         // w = M_rg g + M_gr^T g
    v1 += M[(size_t)(512+k)*1024 + 512 + t] * gk;           // v(k2=t)
    v2 += M[(size_t)(512+k)*1024 + 768 + t] * gk;           // v(k2=t+256)
  }
  qt1[(size_t)q*256+t]=s1; qt2[(size_t)q*256+t]=s2; qw[(size_t)q*256+t]=sw;
  red[t] = v1*g[t] + v2*g[t+256];
  __syncthreads();
  for (int s=128; s>0; s>>=1){
    if (t < s) red[t] += red[t+s];
    __syncthreads();
  }
  if (t==0) qc[q] = red[0];
}

// ---------------- per-edge logits (one wave per edge) -----------------------
__global__ __launch_bounds__(256) void logits_k(const int* __restrict__ edges, int ebase,
    const float* __restrict__ H, const float* __restrict__ U, const float* __restrict__ Rel,
    const float* __restrict__ Grelc,
    const float* __restrict__ qt1, const float* __restrict__ qt2,
    const float* __restrict__ qw, const float* __restrict__ qc,
    float* __restrict__ logits)
{
  int lane = threadIdx.x & 63;
  int el = blockIdx.x*4 + (threadIdx.x >> 6);
  int e  = ebase + el;
  int q   = edges[(size_t)e*8 + 0];
  int src = edges[(size_t)e*8 + 6];
  int dst = edges[(size_t)e*8 + 7];
  const float4* hs = (const float4*)(H   + (size_t)src*256);
  const float4* hd = (const float4*)(H   + (size_t)dst*256);
  const float4* us = (const float4*)(U   + (size_t)src*256);
  const float4* rl = (const float4*)(Rel + (size_t)e*256);
  const float4* g1 = (const float4*)(Grelc + (size_t)el*768);
  const float4* g2 = g1 + 64;
  const float4* g3 = g1 + 128;
  const float4* t1 = (const float4*)(qt1 + (size_t)q*256);
  const float4* t2 = (const float4*)(qt2 + (size_t)q*256);
  const float4* w4 = (const float4*)(qw  + (size_t)q*256);

  float4 a, b, c, d;
  float s = 0.f;
  a = hd[lane]; b = us[lane]; c = g2[lane]; d = t2[lane];
  s += a.x*(b.x+c.x+d.x) + a.y*(b.y+c.y+d.y) + a.z*(b.z+c.z+d.z) + a.w*(b.w+c.w+d.w);
  a = hs[lane]; b = g1[lane]; c = t1[lane];
  s += a.x*(b.x+c.x) + a.y*(b.y+c.y) + a.z*(b.z+c.z) + a.w*(b.w+c.w);
  a = rl[lane]; b = g3[lane]; c = w4[lane];
  s += a.x*(b.x+c.x) + a.y*(b.y+c.y) + a.z*(b.z+c.z) + a.w*(b.w+c.w);
#pragma unroll
  for (int off=32; off>0; off>>=1) s += __shfl_down(s, off);
  if (lane==0) logits[e] = s + qc[q];
}

// ---------------- segmented softmax over src-node segments ------------------
__global__ void segmax_k(const int* __restrict__ edges, const float* __restrict__ logits,
                         unsigned* __restrict__ menc, int nE)
{
  int e = blockIdx.x*256 + threadIdx.x; if (e >= nE) return;
  atomicMax(menc + edges[(size_t)e*8+6], fenc(logits[e]));
}
__global__ void segexp_k(const int* __restrict__ edges, const float* __restrict__ logits,
                         const unsigned* __restrict__ menc, float* __restrict__ ebuf,
                         float* __restrict__ ssum, int nE)
{
  int e = blockIdx.x*256 + threadIdx.x; if (e >= nE) return;
  int s = edges[(size_t)e*8+6];
  float ex = expf(logits[e] - fdec(menc[s]));
  ebuf[e] = ex;
  atomicAdd(ssum + s, ex);
}
template<int TGT>
__global__ void segsoft_k(const int* __restrict__ edges, const float* __restrict__ ebuf,
                          const float* __restrict__ ssum, float* __restrict__ soft,
                          const float* __restrict__ score, float* __restrict__ target, int nE)
{
  int e = blockIdx.x*256 + threadIdx.x; if (e >= nE) return;
  int s = edges[(size_t)e*8+6];
  float so = ebuf[e] / ssum[s];
  soft[e] = so;
  if (TGT) target[e] = so * score[s];
}

// ---------------- per-query top-64 (bitonic, matches top_k tie order) -------
__global__ __launch_bounds__(256) void topk_k(const float* __restrict__ target,
    const float* __restrict__ soft, const int* __restrict__ edges1,
    float* __restrict__ out0, float* __restrict__ out2, float* __restrict__ out3,
    int* __restrict__ p_src, int* __restrict__ p_dst, float* __restrict__ p_w)
{
  int qb = blockIdx.x, t = threadIdx.x;
  __shared__ float v[256];
  __shared__ int   ix[256];
  v[t] = target[(size_t)qb*256 + t];
  ix[t] = t;
  __syncthreads();
  for (int k=2; k<=256; k<<=1){
    for (int j=k>>1; j>0; j>>=1){
      int ixj = t ^ j;
      if (ixj > t){
        float va=v[t], vb=v[ixj]; int ia=ix[t], ib=ix[ixj];
        bool dir  = ((t & k) == 0);
        bool l_ab = (va > vb) || (va == vb && ia < ib);
        bool sw   = dir ? (!l_ab) : l_ab;
        if (sw){ v[t]=vb; v[ixj]=va; ix[t]=ib; ix[ixj]=ia; }
      }
      __syncthreads();
    }
  }
  if (t < 64){
    int oi = qb*256 + ix[t];
    int o  = qb*64 + t;
    out3[o] = (float)oi;
#pragma unroll
    for (int c2=0;c2<8;++c2) out2[(size_t)o*8 + c2] = (float)edges1[(size_t)oi*8 + c2];
    int s_ = edges1[(size_t)oi*8+6], d_ = edges1[(size_t)oi*8+7];
    p_src[o] = s_; p_dst[o] = d_; p_w[o] = soft[oi];
    atomicAdd(out0 + d_, v[t]);
  }
}

// ---------------- bucketized repr update ------------------------------------
__global__ void bucket_fill(const int* __restrict__ srcarr, int stride, int n,
                            int* __restrict__ counts, int* __restrict__ bucket,
                            int* __restrict__ over, int* __restrict__ n_over)
{
  int e = blockIdx.x*256 + threadIdx.x; if (e >= n) return;
  int s = srcarr[(size_t)e*stride];
  int pos = atomicAdd(counts + s, 1);
  if (pos < BCAP) bucket[(size_t)s*BCAP + pos] = e;
  else { int oi = atomicAdd(n_over, 1); over[oi] = e; }
}

__global__ __launch_bounds__(256) void fused_update(const int* __restrict__ counts,
    const int* __restrict__ bucket, const int* __restrict__ dstarr, int dstride,
    const float* __restrict__ w, const float* __restrict__ Hin, float* __restrict__ Hout)
{
  int lane = threadIdx.x & 63;
  int n = blockIdx.x*4 + (threadIdx.x >> 6);
  if (n >= NN) return;
  int cnt = counts[n];
  float fac = cnt > 0 ? 0.2f : 1.0f;
  float4 h = ((const float4*)(Hin + (size_t)n*256))[lane];
  float4 acc = make_float4(fac*h.x, fac*h.y, fac*h.z, fac*h.w);
  int m = cnt < BCAP ? cnt : BCAP;
  for (int i=0;i<m;++i){
    int e = bucket[(size_t)n*BCAP + i];
    int d = dstarr[(size_t)e*dstride];
    float f = 0.8f * w[e];
    float4 vv = ((const float4*)(Hin + (size_t)d*256))[lane];
    acc.x += f*vv.x; acc.y += f*vv.y; acc.z += f*vv.z; acc.w += f*vv.w;
  }
  ((float4*)(Hout + (size_t)n*256))[lane] = acc;
}

__global__ __launch_bounds__(256) void over_k(const int* __restrict__ over,
    const int* __restrict__ n_over,
    const int* __restrict__ srcarr, int sstride,
    const int* __restrict__ dstarr, int dstride,
    const float* __restrict__ w, const float* __restrict__ Hin, float* __restrict__ Hout)
{
  int lane = threadIdx.x & 63;
  int i = blockIdx.x*4 + (threadIdx.x >> 6);
  if (i >= *n_over) return;
  int e = over[i];
  int s = srcarr[(size_t)e*sstride], d = dstarr[(size_t)e*dstride];
  float f = 0.8f * w[e];
  float4 vv = ((const float4*)(Hin + (size_t)d*256))[lane];
  float* o = Hout + (size_t)s*256 + lane*4;
  atomicAdd(o+0, f*vv.x); atomicAdd(o+1, f*vv.y);
  atomicAdd(o+2, f*vv.z); atomicAdd(o+3, f*vv.w);
}

// ---------------- host launch ------------------------------------------------
extern "C" void kernel_launch(void* const* d_in, const int* in_sizes, int n_in,
                              void* d_out, int out_size, void* d_ws, size_t ws_size,
                              hipStream_t stream)
{
  const float* score = (const float*)d_in[0];
  const float* H0    = (const float*)d_in[1];
  const int*   edges0= (const int*)d_in[2];
  const int*   edges1= (const int*)d_in[3];
  const float* rel0  = (const float*)d_in[4];
  const float* rel1  = (const float*)d_in[5];
  const float* qst   = (const float*)d_in[6];
  const float* qr    = (const float*)d_in[7];
  const float* Wq    = (const float*)d_in[8];
  const float* Wk    = (const float*)d_in[9];
  const float* Wl    = (const float*)d_in[10];
  const float* bl    = (const float*)d_in[11];
  (void)in_sizes; (void)n_in; (void)out_size; (void)ws_size;

  float* out0 = (float*)d_out;                 // updated_node_score (50000)
  float* out1 = out0 + NN;                     // node_repr (50000*256)
  float* out2 = out1 + (size_t)NN*D;           // pruned_edges (8192*8)
  float* out3 = out2 + (size_t)NQ*ME*8;        // orig_indices (8192)

  float* ws     = (float*)d_ws;
  float* Mbuf   = ws;                          // 1,048,576 f
  float* Wcat   = ws + 1048576;                // 196,608 f
  float* WlT    = ws + 1245184;                // 65,536 f
  float* qt1    = ws + 1310720;
  float* qt2    = ws + 1343488;
  float* qw     = ws + 1376256;
  float* qc     = ws + 1409024;
  float* logits = ws + 1409152;
  float* ebuf   = ws + 1441920;
  float* soft   = ws + 1474688;
  float* target = ws + 1507456;
  unsigned* menc= (unsigned*)(ws + 1540224);   // 50,000
  float* ssum   = ws + 1590224;                // 50,000
  int* p_src    = (int*)(ws + 1640224);        // 8,192
  int* p_dst    = (int*)(ws + 1648416);
  float* p_w    = ws + 1656608;                // 8,192  (ends 1,664,800)
  float* U      = ws + 1677312;                // 12,800,000 f (51.2 MB region)
  float* Hnew   = ws + 14477312;               // 12,800,000 f
  float* Grelc  = ws + 27277312;               // 6,291,456 f (25.2 MB region)
  float* Hpre   = U;                           // alias: U dead before Hpre written
  double* Mpart = (double*)U;                  // alias: 4x1M doubles (33.5MB <= 51.2MB)
  // bucket machinery aliases the Grelc region (dead between logits phases):
  int* counts = (int*)Grelc;                   // +0      .. 50,000
  int* n_over = (int*)(Grelc + 50000);         // +50,000 .. 1
  int* over   = (int*)(Grelc + 50056);         // +50,056 .. 32,768
  int* bucket = (int*)(Grelc + 100000);        // +100,000 .. 1,600,000 (fits in 6.29M)

  hipMemsetAsync(out0, 0, (size_t)NN*4, stream);
  hipMemsetAsync(menc, 0, (size_t)NN*4, stream);
  hipMemsetAsync(ssum, 0, (size_t)NN*4, stream);

  // precompute M = Wq^T Wk (split-K fp64), Wcat, WlT, query tables
  gemm_tn_split<<<dim3(16,16,4), 256, 0, stream>>>(Wq, Wk, Mpart);
  reduce_m<<<4096, 256, 0, stream>>>(Mpart, Mbuf);
  build_wcat<<<768, 256, 0, stream>>>(Mbuf, Wcat);
  build_wlt<<<256, 256, 0, stream>>>(Wl, WlT);
  query_tables<<<NQ, 256, 0, stream>>>(Mbuf, qst, qr, qt1, qt2, qw, qc);

  // ---- call 1: edges1 / rel1 / H0 ----
  gemm128<0><<<dim3(391,2), 256, 0, stream>>>(H0, 256, Mbuf, 1024, U, 256, NN, 256, nullptr);
  for (int c = 0; c < NCHUNKS; ++c){
    gemm128<0><<<dim3(64,6), 256, 0, stream>>>(
        rel1 + (size_t)c*CHUNK*256, 256, Wcat, 768, Grelc, 768, CHUNK, 256, nullptr);
    logits_k<<<CHUNK/4, 256, 0, stream>>>(edges1, c*CHUNK, H0, U, rel1, Grelc,
                                          qt1, qt2, qw, qc, logits);
  }
  segmax_k<<<NE/256, 256, 0, stream>>>(edges1, logits, menc, NE);
  segexp_k<<<NE/256, 256, 0, stream>>>(edges1, logits, menc, ebuf, ssum, NE);
  segsoft_k<1><<<NE/256, 256, 0, stream>>>(edges1, ebuf, ssum, soft, score, target, NE);

  topk_k<<<NQ, 256, 0, stream>>>(target, soft, edges1, out0, out2, out3, p_src, p_dst, p_w);

  // repr update 1 (Grelc region now dead -> bucket machinery)
  hipMemsetAsync(counts, 0, (size_t)NN*4, stream);
  hipMemsetAsync(n_over, 0, 4, stream);
  bucket_fill<<<(NQ*ME+255)/256, 256, 0, stream>>>(p_src, 1, NQ*ME, counts, bucket, over, n_over);
  fused_update<<<(NN+3)/4, 256, 0, stream>>>(counts, bucket, p_dst, 1, p_w, H0, Hnew);
  over_k<<<(NQ*ME)/4, 256, 0, stream>>>(over, n_over, p_src, 1, p_dst, 1, p_w, H0, Hnew);

  // re-init for call 2
  hipMemsetAsync(menc, 0, (size_t)NN*4, stream);
  hipMemsetAsync(ssum, 0, (size_t)NN*4, stream);

  // ---- call 2: edges0 / rel0 / Hnew ----
  gemm128<0><<<dim3(391,2), 256, 0, stream>>>(Hnew, 256, Mbuf, 1024, U, 256, NN, 256, nullptr);
  for (int c = 0; c < NCHUNKS; ++c){
    gemm128<0><<<dim3(64,6), 256, 0, stream>>>(
        rel0 + (size_t)c*CHUNK*256, 256, Wcat, 768, Grelc, 768, CHUNK, 256, nullptr);
    logits_k<<<CHUNK/4, 256, 0, stream>>>(edges0, c*CHUNK, Hnew, U, rel0, Grelc,
                                          qt1, qt2, qw, qc, logits);
  }
  segmax_k<<<NE/256, 256, 0, stream>>>(edges0, logits, menc, NE);
  segexp_k<<<NE/256, 256, 0, stream>>>(edges0, logits, menc, ebuf, ssum, NE);
  segsoft_k<0><<<NE/256, 256, 0, stream>>>(edges0, ebuf, ssum, soft, nullptr, nullptr, NE);

  // repr update 2 (Grelc dead again)
  hipMemsetAsync(counts, 0, (size_t)NN*4, stream);
  hipMemsetAsync(n_over, 0, 4, stream);
  bucket_fill<<<NE/256, 256, 0, stream>>>(edges0 + 6, 8, NE, counts, bucket, over, n_over);
  fused_update<<<(NN+3)/4, 256, 0, stream>>>(counts, bucket, edges0 + 7, 8, soft, Hnew, Hpre);
  over_k<<<NE/4, 256, 0, stream>>>(over, n_over, edges0 + 6, 8, edges0 + 7, 8, soft, Hnew, Hpre);

  // final: out1 = leaky_relu(Hpre @ Wl^T + bl)
  gemm128<1><<<dim3(391,2), 256, 0, stream>>>(Hpre, 256, WlT, 256, out1, 256, NN, 256, bl);
}

// Round 3
// 1069.690 us; speedup vs baseline: 1.2321x; 1.1452x over previous
//
#include <hip/hip_runtime.h>

#define NN 50000
#define D 256
#define NQ 128
#define PG 256
#define NE 32768
#define ME 64
#define CHUNK 8192
#define NCHUNKS 4
#define BCAP 32

__device__ __forceinline__ unsigned fenc(float f){
  unsigned b = __float_as_uint(f);
  return (b & 0x80000000u) ? ~b : (b | 0x80000000u);
}
__device__ __forceinline__ float fdec(unsigned u){
  unsigned b = (u & 0x80000000u) ? (u & 0x7fffffffu) : ~u;
  return __uint_as_float(b);
}

// ---- fp32 GEMM: C = A(MxK) @ B(KxN), 128x128 tile, 8x8/thread --------------
// Conflict-free LDS: As k-major pad-132 (scalar staged, b128 frag loads);
// Bs row-major pad-132 staged column-per-thread (scalar), fragments strided
// Bs[kk][tx+16j]. Global prefetch pipelined one K-tile ahead.
template<int EPI>
__global__ __launch_bounds__(256) void gemm128(const float* __restrict__ A, int lda,
                                               const float* __restrict__ B, int ldb,
                                               float* __restrict__ C, int ldc,
                                               int Mrows, int Kdim,
                                               const float* __restrict__ bias)
{
  __shared__ float As[16][132];
  __shared__ float Bs[16][132];
  const int tid = threadIdx.x;
  const int rb = blockIdx.x * 128, cb = blockIdx.y * 128;
  const int tx = tid & 15, ty = tid >> 4;        // C: rows ty*8+i, cols tx+16j
  const int a_r = tid >> 1, a_k = (tid & 1) * 8; // A stage: row a_r, 8 k-floats
  const int b_c = tid & 127, b_r0 = (tid >> 7) * 8; // B stage: col b_c, rows b_r0..+7
  const int arow = rb + a_r;
  const bool a_ok = arow < Mrows;

  float4 pa0 = make_float4(0.f,0.f,0.f,0.f), pa1 = pa0;
  float pb[8];
  if (a_ok) {
    pa0 = *(const float4*)(A + (size_t)arow*lda + a_k);
    pa1 = *(const float4*)(A + (size_t)arow*lda + a_k + 4);
  }
#pragma unroll
  for (int j=0;j<8;++j) pb[j] = B[(size_t)(b_r0+j)*ldb + cb + b_c];

  float acc[8][8] = {};
  const int NK = Kdim >> 4;
  for (int t0 = 0; t0 < NK; ++t0) {
    __syncthreads();   // prev iter's LDS reads done; prefetch arrival enforced here
    As[a_k+0][a_r]=pa0.x; As[a_k+1][a_r]=pa0.y; As[a_k+2][a_r]=pa0.z; As[a_k+3][a_r]=pa0.w;
    As[a_k+4][a_r]=pa1.x; As[a_k+5][a_r]=pa1.y; As[a_k+6][a_r]=pa1.z; As[a_k+7][a_r]=pa1.w;
#pragma unroll
    for (int j=0;j<8;++j) Bs[b_r0+j][b_c] = pb[j];
    __syncthreads();
    if (t0 + 1 < NK) {
      const int k0 = (t0+1) << 4;
      if (a_ok) {
        pa0 = *(const float4*)(A + (size_t)arow*lda + k0 + a_k);
        pa1 = *(const float4*)(A + (size_t)arow*lda + k0 + a_k + 4);
      }
#pragma unroll
      for (int j=0;j<8;++j) pb[j] = B[(size_t)(k0+b_r0+j)*ldb + cb + b_c];
    }
#pragma unroll
    for (int kk=0; kk<16; ++kk){
      float a[8], b[8];
      *(float4*)&a[0] = *(const float4*)&As[kk][ty*8];
      *(float4*)&a[4] = *(const float4*)&As[kk][ty*8+4];
#pragma unroll
      for (int j=0;j<8;++j) b[j] = Bs[kk][tx + 16*j];
#pragma unroll
      for (int i=0;i<8;++i)
#pragma unroll
        for (int j=0;j<8;++j) acc[i][j] += a[i]*b[j];
    }
  }
#pragma unroll
  for (int i=0;i<8;++i){
    int row = rb + ty*8 + i;
    if (row < Mrows){
#pragma unroll
      for (int j=0;j<8;++j){
        float v = acc[i][j];
        int col = cb + tx + 16*j;
        if (EPI==1){ v += bias[col]; v = v > 0.f ? v : 0.01f*v; }
        C[(size_t)row*ldc + col] = v;
      }
    }
  }
}

// ------- M = Wq^T @ Wk (1024x1024), fp64 accumulate, split-K x4 -------------
__global__ __launch_bounds__(256) void gemm_tn_split(const float* __restrict__ A,
                                                     const float* __restrict__ B,
                                                     double* __restrict__ Cpart)
{
  __shared__ float As[16][68];
  __shared__ float Bs[16][68];
  const int tid = threadIdx.x;
  const int rb = blockIdx.x * 64, cb = blockIdx.y * 64;
  const int z  = blockIdx.z;
  const int ty = tid >> 4, tx = tid & 15;
  const int aj = tid >> 4, akk = (tid & 15) << 2;
  double acc[4][4] = {};
  const int jbeg = z * 256, jend = jbeg + 256;
  for (int j0 = jbeg; j0 < jend; j0 += 16) {
    float4 av = *(const float4*)(A + (size_t)(j0+aj)*1024 + rb + akk);
    As[aj][akk+0]=av.x; As[aj][akk+1]=av.y; As[aj][akk+2]=av.z; As[aj][akk+3]=av.w;
    float4 bv = *(const float4*)(B + (size_t)(j0+aj)*1024 + cb + akk);
    Bs[aj][akk+0]=bv.x; Bs[aj][akk+1]=bv.y; Bs[aj][akk+2]=bv.z; Bs[aj][akk+3]=bv.w;
    __syncthreads();
#pragma unroll
    for (int jj=0; jj<16; ++jj){
      float a0=As[jj][ty*4+0],a1=As[jj][ty*4+1],a2=As[jj][ty*4+2],a3=As[jj][ty*4+3];
      float b0=Bs[jj][tx*4+0],b1=Bs[jj][tx*4+1],b2=Bs[jj][tx*4+2],b3=Bs[jj][tx*4+3];
      acc[0][0]+=(double)a0*b0; acc[0][1]+=(double)a0*b1; acc[0][2]+=(double)a0*b2; acc[0][3]+=(double)a0*b3;
      acc[1][0]+=(double)a1*b0; acc[1][1]+=(double)a1*b1; acc[1][2]+=(double)a1*b2; acc[1][3]+=(double)a1*b3;
      acc[2][0]+=(double)a2*b0; acc[2][1]+=(double)a2*b1; acc[2][2]+=(double)a2*b2; acc[2][3]+=(double)a2*b3;
      acc[3][0]+=(double)a3*b0; acc[3][1]+=(double)a3*b1; acc[3][2]+=(double)a3*b2; acc[3][3]+=(double)a3*b3;
    }
    __syncthreads();
  }
  double* Cz = Cpart + (size_t)z * 1048576;
#pragma unroll
  for (int i=0;i<4;++i)
#pragma unroll
    for (int j=0;j<4;++j)
      Cz[(size_t)(rb+ty*4+i)*1024 + cb+tx*4+j] = acc[i][j];
}

__global__ void reduce_m(const double* __restrict__ P, float* __restrict__ Mout)
{
  int i = blockIdx.x*256 + threadIdx.x;
  Mout[i] = (float)(P[i] + P[i+1048576] + P[i+2097152] + P[i+3145728]);
}

// ---------------- build Wcat (256 x 768): cols [a1 | a2 | a3] ----------------
__global__ void build_wcat(const float* __restrict__ M, float* __restrict__ Wcat)
{
  int idx = blockIdx.x*256 + threadIdx.x;
  if (idx >= 256*768) return;
  int k = idx / 768, j = idx % 768;
  float v;
  if (j < 256)       v = M[(size_t)j*1024 + 256 + k];
  else if (j < 512)  v = M[(size_t)(256+k)*1024 + (j-256)];
  else               v = M[(size_t)(256+(j-512))*1024 + 256+k];
  Wcat[idx] = v;
}

__global__ void build_wlt(const float* __restrict__ Wl, float* __restrict__ WlT)
{
  int idx = blockIdx.x*256 + threadIdx.x;
  if (idx >= 256*256) return;
  int k = idx / 256, j = idx % 256;
  WlT[idx] = Wl[(size_t)j*256 + k];
}

// ---------------- per-query tables t1,t2,w (128x256) and c (128) ------------
__global__ __launch_bounds__(256) void query_tables(const float* __restrict__ M,
    const float* __restrict__ qst, const float* __restrict__ qr,
    float* __restrict__ qt1, float* __restrict__ qt2, float* __restrict__ qw,
    float* __restrict__ qc)
{
  int q = blockIdx.x, t = threadIdx.x;
  __shared__ float g[512];
  __shared__ float red[256];
  g[t]       = qst[(size_t)q*256 + t];
  g[t + 256] = qr [(size_t)q*256 + t];
  __syncthreads();
  float s1=0.f, s2=0.f, sw=0.f, v1=0.f, v2=0.f;
  for (int k=0;k<512;++k){
    float gk = g[k];
    s1 += M[(size_t)t*1024 + 512 + k] * gk;
    s2 += M[(size_t)(512+k)*1024 + t] * gk;
    sw += (M[(size_t)(256+t)*1024 + 512 + k] +
           M[(size_t)(512+k)*1024 + 256 + t]) * gk;
    v1 += M[(size_t)(512+k)*1024 + 512 + t] * gk;
    v2 += M[(size_t)(512+k)*1024 + 768 + t] * gk;
  }
  qt1[(size_t)q*256+t]=s1; qt2[(size_t)q*256+t]=s2; qw[(size_t)q*256+t]=sw;
  red[t] = v1*g[t] + v2*g[t+256];
  __syncthreads();
  for (int s=128; s>0; s>>=1){
    if (t < s) red[t] += red[t+s];
    __syncthreads();
  }
  if (t==0) qc[q] = red[0];
}

// ---------------- per-edge logits (one wave per edge) -----------------------
__global__ __launch_bounds__(256) void logits_k(const int* __restrict__ edges, int ebase,
    const float* __restrict__ H, const float* __restrict__ U, const float* __restrict__ Rel,
    const float* __restrict__ Grelc,
    const float* __restrict__ qt1, const float* __restrict__ qt2,
    const float* __restrict__ qw, const float* __restrict__ qc,
    float* __restrict__ logits)
{
  int lane = threadIdx.x & 63;
  int el = blockIdx.x*4 + (threadIdx.x >> 6);
  int e  = ebase + el;
  int q   = edges[(size_t)e*8 + 0];
  int src = edges[(size_t)e*8 + 6];
  int dst = edges[(size_t)e*8 + 7];
  const float4* hs = (const float4*)(H   + (size_t)src*256);
  const float4* hd = (const float4*)(H   + (size_t)dst*256);
  const float4* us = (const float4*)(U   + (size_t)src*256);
  const float4* rl = (const float4*)(Rel + (size_t)e*256);
  const float4* g1 = (const float4*)(Grelc + (size_t)el*768);
  const float4* g2 = g1 + 64;
  const float4* g3 = g1 + 128;
  const float4* t1 = (const float4*)(qt1 + (size_t)q*256);
  const float4* t2 = (const float4*)(qt2 + (size_t)q*256);
  const float4* w4 = (const float4*)(qw  + (size_t)q*256);

  float4 a, b, c, d;
  float s = 0.f;
  a = hd[lane]; b = us[lane]; c = g2[lane]; d = t2[lane];
  s += a.x*(b.x+c.x+d.x) + a.y*(b.y+c.y+d.y) + a.z*(b.z+c.z+d.z) + a.w*(b.w+c.w+d.w);
  a = hs[lane]; b = g1[lane]; c = t1[lane];
  s += a.x*(b.x+c.x) + a.y*(b.y+c.y) + a.z*(b.z+c.z) + a.w*(b.w+c.w);
  a = rl[lane]; b = g3[lane]; c = w4[lane];
  s += a.x*(b.x+c.x) + a.y*(b.y+c.y) + a.z*(b.z+c.z) + a.w*(b.w+c.w);
#pragma unroll
  for (int off=32; off>0; off>>=1) s += __shfl_down(s, off);
  if (lane==0) logits[e] = s + qc[q];
}

// ---------------- segmented softmax over src-node segments ------------------
__global__ void segmax_k(const int* __restrict__ edges, const float* __restrict__ logits,
                         unsigned* __restrict__ menc, int nE)
{
  int e = blockIdx.x*256 + threadIdx.x; if (e >= nE) return;
  atomicMax(menc + edges[(size_t)e*8+6], fenc(logits[e]));
}
__global__ void segexp_k(const int* __restrict__ edges, const float* __restrict__ logits,
                         const unsigned* __restrict__ menc, float* __restrict__ ebuf,
                         float* __restrict__ ssum, int nE)
{
  int e = blockIdx.x*256 + threadIdx.x; if (e >= nE) return;
  int s = edges[(size_t)e*8+6];
  float ex = expf(logits[e] - fdec(menc[s]));
  ebuf[e] = ex;
  atomicAdd(ssum + s, ex);
}
template<int TGT>
__global__ void segsoft_k(const int* __restrict__ edges, const float* __restrict__ ebuf,
                          const float* __restrict__ ssum, float* __restrict__ soft,
                          const float* __restrict__ score, float* __restrict__ target, int nE)
{
  int e = blockIdx.x*256 + threadIdx.x; if (e >= nE) return;
  int s = edges[(size_t)e*8+6];
  float so = ebuf[e] / ssum[s];
  soft[e] = so;
  if (TGT) target[e] = so * score[s];
}

// ---------------- per-query top-64 (bitonic, matches top_k tie order) -------
__global__ __launch_bounds__(256) void topk_k(const float* __restrict__ target,
    const float* __restrict__ soft, const int* __restrict__ edges1,
    float* __restrict__ out0, float* __restrict__ out2, float* __restrict__ out3,
    int* __restrict__ p_src, int* __restrict__ p_dst, float* __restrict__ p_w)
{
  int qb = blockIdx.x, t = threadIdx.x;
  __shared__ float v[256];
  __shared__ int   ix[256];
  v[t] = target[(size_t)qb*256 + t];
  ix[t] = t;
  __syncthreads();
  for (int k=2; k<=256; k<<=1){
    for (int j=k>>1; j>0; j>>=1){
      int ixj = t ^ j;
      if (ixj > t){
        float va=v[t], vb=v[ixj]; int ia=ix[t], ib=ix[ixj];
        bool dir  = ((t & k) == 0);
        bool l_ab = (va > vb) || (va == vb && ia < ib);
        bool sw   = dir ? (!l_ab) : l_ab;
        if (sw){ v[t]=vb; v[ixj]=va; ix[t]=ib; ix[ixj]=ia; }
      }
      __syncthreads();
    }
  }
  if (t < 64){
    int oi = qb*256 + ix[t];
    int o  = qb*64 + t;
    out3[o] = (float)oi;
#pragma unroll
    for (int c2=0;c2<8;++c2) out2[(size_t)o*8 + c2] = (float)edges1[(size_t)oi*8 + c2];
    int s_ = edges1[(size_t)oi*8+6], d_ = edges1[(size_t)oi*8+7];
    p_src[o] = s_; p_dst[o] = d_; p_w[o] = soft[oi];
    atomicAdd(out0 + d_, v[t]);
  }
}

// ---------------- bucketized repr update ------------------------------------
__global__ void bucket_fill(const int* __restrict__ srcarr, int stride, int n,
                            int* __restrict__ counts, int* __restrict__ bucket,
                            int* __restrict__ over, int* __restrict__ n_over)
{
  int e = blockIdx.x*256 + threadIdx.x; if (e >= n) return;
  int s = srcarr[(size_t)e*stride];
  int pos = atomicAdd(counts + s, 1);
  if (pos < BCAP) bucket[(size_t)s*BCAP + pos] = e;
  else { int oi = atomicAdd(n_over, 1); over[oi] = e; }
}

__global__ __launch_bounds__(256) void fused_update(const int* __restrict__ counts,
    const int* __restrict__ bucket, const int* __restrict__ dstarr, int dstride,
    const float* __restrict__ w, const float* __restrict__ Hin, float* __restrict__ Hout)
{
  int lane = threadIdx.x & 63;
  int n = blockIdx.x*4 + (threadIdx.x >> 6);
  if (n >= NN) return;
  int cnt = counts[n];
  float fac = cnt > 0 ? 0.2f : 1.0f;
  float4 h = ((const float4*)(Hin + (size_t)n*256))[lane];
  float4 acc = make_float4(fac*h.x, fac*h.y, fac*h.z, fac*h.w);
  int m = cnt < BCAP ? cnt : BCAP;
  for (int i=0;i<m;++i){
    int e = bucket[(size_t)n*BCAP + i];
    int d = dstarr[(size_t)e*dstride];
    float f = 0.8f * w[e];
    float4 vv = ((const float4*)(Hin + (size_t)d*256))[lane];
    acc.x += f*vv.x; acc.y += f*vv.y; acc.z += f*vv.z; acc.w += f*vv.w;
  }
  ((float4*)(Hout + (size_t)n*256))[lane] = acc;
}

__global__ __launch_bounds__(256) void over_k(const int* __restrict__ over,
    const int* __restrict__ n_over,
    const int* __restrict__ srcarr, int sstride,
    const int* __restrict__ dstarr, int dstride,
    const float* __restrict__ w, const float* __restrict__ Hin, float* __restrict__ Hout)
{
  int lane = threadIdx.x & 63;
  int i = blockIdx.x*4 + (threadIdx.x >> 6);
  if (i >= *n_over) return;
  int e = over[i];
  int s = srcarr[(size_t)e*sstride], d = dstarr[(size_t)e*dstride];
  float f = 0.8f * w[e];
  float4 vv = ((const float4*)(Hin + (size_t)d*256))[lane];
  float* o = Hout + (size_t)s*256 + lane*4;
  atomicAdd(o+0, f*vv.x); atomicAdd(o+1, f*vv.y);
  atomicAdd(o+2, f*vv.z); atomicAdd(o+3, f*vv.w);
}

// ---------------- host launch ------------------------------------------------
extern "C" void kernel_launch(void* const* d_in, const int* in_sizes, int n_in,
                              void* d_out, int out_size, void* d_ws, size_t ws_size,
                              hipStream_t stream)
{
  const float* score = (const float*)d_in[0];
  const float* H0    = (const float*)d_in[1];
  const int*   edges0= (const int*)d_in[2];
  const int*   edges1= (const int*)d_in[3];
  const float* rel0  = (const float*)d_in[4];
  const float* rel1  = (const float*)d_in[5];
  const float* qst   = (const float*)d_in[6];
  const float* qr    = (const float*)d_in[7];
  const float* Wq    = (const float*)d_in[8];
  const float* Wk    = (const float*)d_in[9];
  const float* Wl    = (const float*)d_in[10];
  const float* bl    = (const float*)d_in[11];
  (void)in_sizes; (void)n_in; (void)out_size;

  float* out0 = (float*)d_out;
  float* out1 = out0 + NN;
  float* out2 = out1 + (size_t)NN*D;
  float* out3 = out2 + (size_t)NQ*ME*8;

  float* ws     = (float*)d_ws;
  float* Mbuf   = ws;
  float* Wcat   = ws + 1048576;
  float* WlT    = ws + 1245184;
  float* qt1    = ws + 1310720;
  float* qt2    = ws + 1343488;
  float* qw     = ws + 1376256;
  float* qc     = ws + 1409024;
  float* logits = ws + 1409152;
  float* ebuf   = ws + 1441920;
  float* soft   = ws + 1474688;
  float* target = ws + 1507456;
  unsigned* menc= (unsigned*)(ws + 1540224);
  float* ssum   = ws + 1590224;
  int* p_src    = (int*)(ws + 1640224);
  int* p_dst    = (int*)(ws + 1648416);
  float* p_w    = ws + 1656608;
  float* U      = ws + 1677312;                // 12.8M floats
  float* Hnew   = ws + 14477312;               // 12.8M floats
  float* Grelc  = ws + 27277312;               // chunk: 6.29M / full: 25.17M floats
  float* Hpre   = U;
  double* Mpart = (double*)U;
  int* counts = (int*)Grelc;
  int* n_over = (int*)(Grelc + 50000);
  int* over   = (int*)(Grelc + 50056);
  int* bucket = (int*)(Grelc + 100000);

  // full-size Grelc (32768x768) needs ws >= (27,277,312 + 25,165,824) floats
  const bool full = ws_size >= (size_t)(27277312 + 25165824) * 4ULL;

  hipMemsetAsync(out0, 0, (size_t)NN*4, stream);
  hipMemsetAsync(menc, 0, (size_t)NN*4, stream);
  hipMemsetAsync(ssum, 0, (size_t)NN*4, stream);

  gemm_tn_split<<<dim3(16,16,4), 256, 0, stream>>>(Wq, Wk, Mpart);
  reduce_m<<<4096, 256, 0, stream>>>(Mpart, Mbuf);
  build_wcat<<<768, 256, 0, stream>>>(Mbuf, Wcat);
  build_wlt<<<256, 256, 0, stream>>>(Wl, WlT);
  query_tables<<<NQ, 256, 0, stream>>>(Mbuf, qst, qr, qt1, qt2, qw, qc);

  // ---- call 1: edges1 / rel1 / H0 ----
  gemm128<0><<<dim3(391,2), 256, 0, stream>>>(H0, 256, Mbuf, 1024, U, 256, NN, 256, nullptr);
  if (full) {
    gemm128<0><<<dim3(256,6), 256, 0, stream>>>(rel1, 256, Wcat, 768, Grelc, 768, NE, 256, nullptr);
    logits_k<<<NE/4, 256, 0, stream>>>(edges1, 0, H0, U, rel1, Grelc, qt1, qt2, qw, qc, logits);
  } else {
    for (int c = 0; c < NCHUNKS; ++c){
      gemm128<0><<<dim3(64,6), 256, 0, stream>>>(
          rel1 + (size_t)c*CHUNK*256, 256, Wcat, 768, Grelc, 768, CHUNK, 256, nullptr);
      logits_k<<<CHUNK/4, 256, 0, stream>>>(edges1, c*CHUNK, H0, U, rel1, Grelc,
                                            qt1, qt2, qw, qc, logits);
    }
  }
  segmax_k<<<NE/256, 256, 0, stream>>>(edges1, logits, menc, NE);
  segexp_k<<<NE/256, 256, 0, stream>>>(edges1, logits, menc, ebuf, ssum, NE);
  segsoft_k<1><<<NE/256, 256, 0, stream>>>(edges1, ebuf, ssum, soft, score, target, NE);

  topk_k<<<NQ, 256, 0, stream>>>(target, soft, edges1, out0, out2, out3, p_src, p_dst, p_w);

  hipMemsetAsync(counts, 0, (size_t)NN*4, stream);
  hipMemsetAsync(n_over, 0, 4, stream);
  bucket_fill<<<(NQ*ME+255)/256, 256, 0, stream>>>(p_src, 1, NQ*ME, counts, bucket, over, n_over);
  fused_update<<<(NN+3)/4, 256, 0, stream>>>(counts, bucket, p_dst, 1, p_w, H0, Hnew);
  over_k<<<(NQ*ME)/4, 256, 0, stream>>>(over, n_over, p_src, 1, p_dst, 1, p_w, H0, Hnew);

  hipMemsetAsync(menc, 0, (size_t)NN*4, stream);
  hipMemsetAsync(ssum, 0, (size_t)NN*4, stream);

  // ---- call 2: edges0 / rel0 / Hnew ----
  gemm128<0><<<dim3(391,2), 256, 0, stream>>>(Hnew, 256, Mbuf, 1024, U, 256, NN, 256, nullptr);
  if (full) {
    gemm128<0><<<dim3(256,6), 256, 0, stream>>>(rel0, 256, Wcat, 768, Grelc, 768, NE, 256, nullptr);
    logits_k<<<NE/4, 256, 0, stream>>>(edges0, 0, Hnew, U, rel0, Grelc, qt1, qt2, qw, qc, logits);
  } else {
    for (int c = 0; c < NCHUNKS; ++c){
      gemm128<0><<<dim3(64,6), 256, 0, stream>>>(
          rel0 + (size_t)c*CHUNK*256, 256, Wcat, 768, Grelc, 768, CHUNK, 256, nullptr);
      logits_k<<<CHUNK/4, 256, 0, stream>>>(edges0, c*CHUNK, Hnew, U, rel0, Grelc,
                                            qt1, qt2, qw, qc, logits);
    }
  }
  segmax_k<<<NE/256, 256, 0, stream>>>(edges0, logits, menc, NE);
  segexp_k<<<NE/256, 256, 0, stream>>>(edges0, logits, menc, ebuf, ssum, NE);
  segsoft_k<0><<<NE/256, 256, 0, stream>>>(edges0, ebuf, ssum, soft, nullptr, nullptr, NE);

  hipMemsetAsync(counts, 0, (size_t)NN*4, stream);
  hipMemsetAsync(n_over, 0, 4, stream);
  bucket_fill<<<NE/256, 256, 0, stream>>>(edges0 + 6, 8, NE, counts, bucket, over, n_over);
  fused_update<<<(NN+3)/4, 256, 0, stream>>>(counts, bucket, edges0 + 7, 8, soft, Hnew, Hpre);
  over_k<<<NE/4, 256, 0, stream>>>(over, n_over, edges0 + 6, 8, edges0 + 7, 8, soft, Hnew, Hpre);

  gemm128<1><<<dim3(391,2), 256, 0, stream>>>(Hpre, 256, WlT, 256, out1, 256, NN, 256, bl);
}

// Round 4
// 739.211 us; speedup vs baseline: 1.7829x; 1.4471x over previous
//
#include <hip/hip_runtime.h>

#define NN 50000
#define D 256
#define NQ 128
#define PG 256
#define NE 32768
#define ME 64
#define BCAP 32
#define KDIM 256
#define NKT 8

typedef _Float16 f16;
typedef __attribute__((ext_vector_type(4))) _Float16 f16x4;
typedef __attribute__((ext_vector_type(8))) _Float16 f16x8;
typedef __attribute__((ext_vector_type(4))) float f32x4;

#define MFMA16(a,b,c) __builtin_amdgcn_mfma_f32_16x16x32_f16(a,b,c,0,0,0)

__device__ __forceinline__ f16x8 zero8(){
  f16x8 z;
#pragma unroll
  for (int i=0;i<8;++i) z[i] = (_Float16)0.f;
  return z;
}
__device__ __forceinline__ unsigned fenc(float f){
  unsigned b = __float_as_uint(f);
  return (b & 0x80000000u) ? ~b : (b | 0x80000000u);
}
__device__ __forceinline__ float fdec(unsigned u){
  unsigned b = (u & 0x80000000u) ? (u & 0x7fffffffu) : ~u;
  return __uint_as_float(b);
}

// ---------- fp16x3 MFMA GEMM: C(f32) = (Ah+Al)(M x 256) @ (Bh+Bl)^T ---------
// BT is N x 256 row-major (pre-transposed). Tile 128x128, 4 waves, each wave
// a 64x64 quadrant = 4x4 MFMA tiles of 16x16x32. LDS stride 40 f16 (80 B,
// 16B-aligned, 2-way-max bank aliasing = free).
template<int EPI>
__global__ __launch_bounds__(256) void hgemm(const f16* __restrict__ Ah, const f16* __restrict__ Al,
                                             int Mrows,
                                             const f16* __restrict__ Bh, const f16* __restrict__ Bl,
                                             float* __restrict__ C, int ldc,
                                             const float* __restrict__ bias)
{
  __shared__ f16 AsH[128*40], AsL[128*40], BsH[128*40], BsL[128*40];
  const int tid = threadIdx.x;
  const int rb = blockIdx.x*128, cb = blockIdx.y*128;
  const int row = tid >> 1, ko = (tid & 1)*16;
  const bool aok = (rb + row) < Mrows;
  const int lane = tid & 63, wv = tid >> 6;
  const int qr = (wv & 1)*64, qc = (wv >> 1)*64;
  const int lm = lane & 15, qd = lane >> 4;

  const f16* gAh = Ah + (size_t)(rb+row)*KDIM + ko;
  const f16* gAl = Al + (size_t)(rb+row)*KDIM + ko;
  const f16* gBh = Bh + (size_t)(cb+row)*KDIM + ko;
  const f16* gBl = Bl + (size_t)(cb+row)*KDIM + ko;

  f16x8 pah0=zero8(), pah1=zero8(), pal0=zero8(), pal1=zero8();
  f16x8 pbh0, pbh1, pbl0, pbl1;
  if (aok){ pah0 = *(const f16x8*)gAh; pah1 = *(const f16x8*)(gAh+8);
            pal0 = *(const f16x8*)gAl; pal1 = *(const f16x8*)(gAl+8); }
  pbh0 = *(const f16x8*)gBh; pbh1 = *(const f16x8*)(gBh+8);
  pbl0 = *(const f16x8*)gBl; pbl1 = *(const f16x8*)(gBl+8);

  f32x4 acc[4][4];
#pragma unroll
  for (int t=0;t<4;++t)
#pragma unroll
    for (int u=0;u<4;++u)
#pragma unroll
      for (int r=0;r<4;++r) acc[t][u][r] = 0.f;

  const int wbase = row*40 + ko;
  for (int kt = 0; kt < NKT; ++kt){
    __syncthreads();
    *(f16x8*)(AsH + wbase) = pah0; *(f16x8*)(AsH + wbase + 8) = pah1;
    *(f16x8*)(AsL + wbase) = pal0; *(f16x8*)(AsL + wbase + 8) = pal1;
    *(f16x8*)(BsH + wbase) = pbh0; *(f16x8*)(BsH + wbase + 8) = pbh1;
    *(f16x8*)(BsL + wbase) = pbl0; *(f16x8*)(BsL + wbase + 8) = pbl1;
    __syncthreads();
    if (kt+1 < NKT){
      const int k0 = (kt+1)*32;
      if (aok){ pah0 = *(const f16x8*)(gAh + k0); pah1 = *(const f16x8*)(gAh + k0 + 8);
                pal0 = *(const f16x8*)(gAl + k0); pal1 = *(const f16x8*)(gAl + k0 + 8); }
      pbh0 = *(const f16x8*)(gBh + k0); pbh1 = *(const f16x8*)(gBh + k0 + 8);
      pbl0 = *(const f16x8*)(gBl + k0); pbl1 = *(const f16x8*)(gBl + k0 + 8);
    }
    f16x8 fah[4], fal[4], fbh[4], fbl[4];
#pragma unroll
    for (int t=0;t<4;++t){
      int off = (qr + t*16 + lm)*40 + qd*8;
      fah[t] = *(const f16x8*)(AsH + off);
      fal[t] = *(const f16x8*)(AsL + off);
    }
#pragma unroll
    for (int u=0;u<4;++u){
      int off = (qc + u*16 + lm)*40 + qd*8;
      fbh[u] = *(const f16x8*)(BsH + off);
      fbl[u] = *(const f16x8*)(BsL + off);
    }
#pragma unroll
    for (int t=0;t<4;++t)
#pragma unroll
      for (int u=0;u<4;++u){
        acc[t][u] = MFMA16(fah[t], fbh[u], acc[t][u]);
        acc[t][u] = MFMA16(fah[t], fbl[u], acc[t][u]);
        acc[t][u] = MFMA16(fal[t], fbh[u], acc[t][u]);
      }
  }
  // epilogue: C/D layout col=lane&15, row=(lane>>4)*4+reg
#pragma unroll
  for (int t=0;t<4;++t){
#pragma unroll
    for (int u=0;u<4;++u){
      int col = cb + qc + u*16 + lm;
      f32x4 v = acc[t][u];
#pragma unroll
      for (int r=0;r<4;++r){
        int rg = rb + qr + t*16 + qd*4 + r;
        if (rg < Mrows){
          float x = v[r];
          if (EPI==1){ x += bias[col]; x = x > 0.f ? x : 0.01f*x; }
          C[(size_t)rg*ldc + col] = x;
        }
      }
    }
  }
}

// ---- rel GEMM with fused logits epilogue: partial = sum_j C[e][j]*X[e][j] ---
// grid (256, 6): by 0,1 -> X=H[src]; 2,3 -> H[dst]; 4,5 -> rel[e].
__global__ __launch_bounds__(256) void hgemm_rel(const f16* __restrict__ Ah, const f16* __restrict__ Al,
                                                 const f16* __restrict__ Bh, const f16* __restrict__ Bl,
                                                 const int* __restrict__ edges,
                                                 const float* __restrict__ H,
                                                 const float* __restrict__ Rel,
                                                 float* __restrict__ logits)
{
  __shared__ f16 AsH[128*40], AsL[128*40], BsH[128*40], BsL[128*40];
  __shared__ int sIdx[128];
  const int tid = threadIdx.x;
  const int rb = blockIdx.x*128, cb = blockIdx.y*128;
  const int sec = blockIdx.y >> 1;
  const int row = tid >> 1, ko = (tid & 1)*16;
  const int lane = tid & 63, wv = tid >> 6;
  const int qr = (wv & 1)*64, qc = (wv >> 1)*64;
  const int lm = lane & 15, qd = lane >> 4;

  if (tid < 128){
    int e = rb + tid;
    sIdx[tid] = (sec==0) ? edges[(size_t)e*8+6] : (sec==1 ? edges[(size_t)e*8+7] : 0);
  }

  const f16* gAh = Ah + (size_t)(rb+row)*KDIM + ko;
  const f16* gAl = Al + (size_t)(rb+row)*KDIM + ko;
  const f16* gBh = Bh + (size_t)(cb+row)*KDIM + ko;
  const f16* gBl = Bl + (size_t)(cb+row)*KDIM + ko;

  f16x8 pah0 = *(const f16x8*)gAh, pah1 = *(const f16x8*)(gAh+8);
  f16x8 pal0 = *(const f16x8*)gAl, pal1 = *(const f16x8*)(gAl+8);
  f16x8 pbh0 = *(const f16x8*)gBh, pbh1 = *(const f16x8*)(gBh+8);
  f16x8 pbl0 = *(const f16x8*)gBl, pbl1 = *(const f16x8*)(gBl+8);

  f32x4 acc[4][4];
#pragma unroll
  for (int t=0;t<4;++t)
#pragma unroll
    for (int u=0;u<4;++u)
#pragma unroll
      for (int r=0;r<4;++r) acc[t][u][r] = 0.f;

  const int wbase = row*40 + ko;
  for (int kt = 0; kt < NKT; ++kt){
    __syncthreads();
    *(f16x8*)(AsH + wbase) = pah0; *(f16x8*)(AsH + wbase + 8) = pah1;
    *(f16x8*)(AsL + wbase) = pal0; *(f16x8*)(AsL + wbase + 8) = pal1;
    *(f16x8*)(BsH + wbase) = pbh0; *(f16x8*)(BsH + wbase + 8) = pbh1;
    *(f16x8*)(BsL + wbase) = pbl0; *(f16x8*)(BsL + wbase + 8) = pbl1;
    __syncthreads();
    if (kt+1 < NKT){
      const int k0 = (kt+1)*32;
      pah0 = *(const f16x8*)(gAh + k0); pah1 = *(const f16x8*)(gAh + k0 + 8);
      pal0 = *(const f16x8*)(gAl + k0); pal1 = *(const f16x8*)(gAl + k0 + 8);
      pbh0 = *(const f16x8*)(gBh + k0); pbh1 = *(const f16x8*)(gBh + k0 + 8);
      pbl0 = *(const f16x8*)(gBl + k0); pbl1 = *(const f16x8*)(gBl + k0 + 8);
    }
    f16x8 fah[4], fal[4], fbh[4], fbl[4];
#pragma unroll
    for (int t=0;t<4;++t){
      int off = (qr + t*16 + lm)*40 + qd*8;
      fah[t] = *(const f16x8*)(AsH + off);
      fal[t] = *(const f16x8*)(AsL + off);
    }
#pragma unroll
    for (int u=0;u<4;++u){
      int off = (qc + u*16 + lm)*40 + qd*8;
      fbh[u] = *(const f16x8*)(BsH + off);
      fbl[u] = *(const f16x8*)(BsL + off);
    }
#pragma unroll
    for (int t=0;t<4;++t)
#pragma unroll
      for (int u=0;u<4;++u){
        acc[t][u] = MFMA16(fah[t], fbh[u], acc[t][u]);
        acc[t][u] = MFMA16(fah[t], fbl[u], acc[t][u]);
        acc[t][u] = MFMA16(fal[t], fbh[u], acc[t][u]);
      }
  }
  // fused dot epilogue
  const int cbase = ((blockIdx.y & 1)*128) + qc + lm;
#pragma unroll
  for (int t=0;t<4;++t){
#pragma unroll
    for (int r=0;r<4;++r){
      int lrow = qr + t*16 + qd*4 + r;
      int e = rb + lrow;
      const float* xb = (sec==2) ? (Rel + (size_t)e*256)
                                 : (H + (size_t)sIdx[lrow]*256);
      float p = acc[t][0][r]*xb[cbase]
              + acc[t][1][r]*xb[cbase+16]
              + acc[t][2][r]*xb[cbase+32]
              + acc[t][3][r]*xb[cbase+48];
      p += __shfl_xor(p, 1); p += __shfl_xor(p, 2);
      p += __shfl_xor(p, 4); p += __shfl_xor(p, 8);
      if (lm == 0) atomicAdd(logits + e, p);
    }
  }
}

// ---------------- fp16 split helpers ----------------------------------------
__global__ void split_f16(const float* __restrict__ X, f16* __restrict__ Xh,
                          f16* __restrict__ Xl, int n)
{
  int i = (blockIdx.x*256 + threadIdx.x)*4;
  if (i >= n) return;
  float4 v = *(const float4*)(X+i);
  f16x4 h, l;
  h[0]=(_Float16)v.x; h[1]=(_Float16)v.y; h[2]=(_Float16)v.z; h[3]=(_Float16)v.w;
  l[0]=(_Float16)(v.x-(float)h[0]); l[1]=(_Float16)(v.y-(float)h[1]);
  l[2]=(_Float16)(v.z-(float)h[2]); l[3]=(_Float16)(v.w-(float)h[3]);
  *(f16x4*)(Xh+i)=h; *(f16x4*)(Xl+i)=l;
}

__global__ void build_bt_mhh(const float* __restrict__ M, f16* __restrict__ Bh, f16* __restrict__ Bl)
{
  int idx = blockIdx.x*256 + threadIdx.x;   // 65536: BT[n][k] = M_hh[k][n]
  int n = idx >> 8, k = idx & 255;
  float v = M[(size_t)k*1024 + n];
  _Float16 h = (_Float16)v;
  Bh[idx] = h; Bl[idx] = (_Float16)(v - (float)h);
}

__global__ void build_bt_wcat(const float* __restrict__ M, f16* __restrict__ Bh, f16* __restrict__ Bl)
{
  int idx = blockIdx.x*256 + threadIdx.x;   // 196608: BT[j][k] = Wcat[k][j]
  int j = idx >> 8, k = idx & 255;
  float v;
  if (j < 256)      v = M[(size_t)j*1024 + 256 + k];            // a1 = M_hr^T
  else if (j < 512) v = M[(size_t)(256+k)*1024 + (j-256)];      // a2 = M_rh
  else              v = M[(size_t)(256 + j-512)*1024 + 256 + k];// a3 = M_rr^T
  _Float16 h = (_Float16)v;
  Bh[idx] = h; Bl[idx] = (_Float16)(v - (float)h);
}

// ------- M = Wq^T @ Wk (1024x1024), fp64 accumulate, split-K x4 -------------
__global__ __launch_bounds__(256) void gemm_tn_split(const float* __restrict__ A,
                                                     const float* __restrict__ B,
                                                     double* __restrict__ Cpart)
{
  __shared__ float As[16][68];
  __shared__ float Bs[16][68];
  const int tid = threadIdx.x;
  const int rb = blockIdx.x * 64, cb = blockIdx.y * 64;
  const int z  = blockIdx.z;
  const int ty = tid >> 4, tx = tid & 15;
  const int aj = tid >> 4, akk = (tid & 15) << 2;
  double acc[4][4] = {};
  const int jbeg = z * 256, jend = jbeg + 256;
  for (int j0 = jbeg; j0 < jend; j0 += 16) {
    float4 av = *(const float4*)(A + (size_t)(j0+aj)*1024 + rb + akk);
    As[aj][akk+0]=av.x; As[aj][akk+1]=av.y; As[aj][akk+2]=av.z; As[aj][akk+3]=av.w;
    float4 bv = *(const float4*)(B + (size_t)(j0+aj)*1024 + cb + akk);
    Bs[aj][akk+0]=bv.x; Bs[aj][akk+1]=bv.y; Bs[aj][akk+2]=bv.z; Bs[aj][akk+3]=bv.w;
    __syncthreads();
#pragma unroll
    for (int jj=0; jj<16; ++jj){
      float a0=As[jj][ty*4+0],a1=As[jj][ty*4+1],a2=As[jj][ty*4+2],a3=As[jj][ty*4+3];
      float b0=Bs[jj][tx*4+0],b1=Bs[jj][tx*4+1],b2=Bs[jj][tx*4+2],b3=Bs[jj][tx*4+3];
      acc[0][0]+=(double)a0*b0; acc[0][1]+=(double)a0*b1; acc[0][2]+=(double)a0*b2; acc[0][3]+=(double)a0*b3;
      acc[1][0]+=(double)a1*b0; acc[1][1]+=(double)a1*b1; acc[1][2]+=(double)a1*b2; acc[1][3]+=(double)a1*b3;
      acc[2][0]+=(double)a2*b0; acc[2][1]+=(double)a2*b1; acc[2][2]+=(double)a2*b2; acc[2][3]+=(double)a2*b3;
      acc[3][0]+=(double)a3*b0; acc[3][1]+=(double)a3*b1; acc[3][2]+=(double)a3*b2; acc[3][3]+=(double)a3*b3;
    }
    __syncthreads();
  }
  double* Cz = Cpart + (size_t)z * 1048576;
#pragma unroll
  for (int i=0;i<4;++i)
#pragma unroll
    for (int j=0;j<4;++j)
      Cz[(size_t)(rb+ty*4+i)*1024 + cb+tx*4+j] = acc[i][j];
}

__global__ void reduce_m(const double* __restrict__ P, float* __restrict__ Mout)
{
  int i = blockIdx.x*256 + threadIdx.x;
  Mout[i] = (float)(P[i] + P[i+1048576] + P[i+2097152] + P[i+3145728]);
}

// ---------------- per-query tables t1,t2,w (128x256) and c (128) ------------
__global__ __launch_bounds__(256) void query_tables(const float* __restrict__ M,
    const float* __restrict__ qst, const float* __restrict__ qr,
    float* __restrict__ qt1, float* __restrict__ qt2, float* __restrict__ qw,
    float* __restrict__ qc)
{
  int q = blockIdx.x, t = threadIdx.x;
  __shared__ float g[512];
  __shared__ float red[256];
  g[t]       = qst[(size_t)q*256 + t];
  g[t + 256] = qr [(size_t)q*256 + t];
  __syncthreads();
  float s1=0.f, s2=0.f, sw=0.f, v1=0.f, v2=0.f;
  for (int k=0;k<512;++k){
    float gk = g[k];
    s1 += M[(size_t)t*1024 + 512 + k] * gk;
    s2 += M[(size_t)(512+k)*1024 + t] * gk;
    sw += (M[(size_t)(256+t)*1024 + 512 + k] +
           M[(size_t)(512+k)*1024 + 256 + t]) * gk;
    v1 += M[(size_t)(512+k)*1024 + 512 + t] * gk;
    v2 += M[(size_t)(512+k)*1024 + 768 + t] * gk;
  }
  qt1[(size_t)q*256+t]=s1; qt2[(size_t)q*256+t]=s2; qw[(size_t)q*256+t]=sw;
  red[t] = v1*g[t] + v2*g[t+256];
  __syncthreads();
  for (int s=128; s>0; s>>=1){
    if (t < s) red[t] += red[t+s];
    __syncthreads();
  }
  if (t==0) qc[q] = red[0];
}

// ---------------- slim per-edge logits (non-g terms) ------------------------
__global__ __launch_bounds__(256) void slim_logits(const int* __restrict__ edges,
    const float* __restrict__ H, const float* __restrict__ U,
    const float* __restrict__ Rel,
    const float* __restrict__ qt1, const float* __restrict__ qt2,
    const float* __restrict__ qw, const float* __restrict__ qc,
    float* __restrict__ logits)
{
  int lane = threadIdx.x & 63;
  int e = blockIdx.x*4 + (threadIdx.x >> 6);
  int q   = edges[(size_t)e*8 + 0];
  int src = edges[(size_t)e*8 + 6];
  int dst = edges[(size_t)e*8 + 7];
  const float4* hs = (const float4*)(H   + (size_t)src*256);
  const float4* hd = (const float4*)(H   + (size_t)dst*256);
  const float4* us = (const float4*)(U   + (size_t)src*256);
  const float4* rl = (const float4*)(Rel + (size_t)e*256);
  const float4* t1 = (const float4*)(qt1 + (size_t)q*256);
  const float4* t2 = (const float4*)(qt2 + (size_t)q*256);
  const float4* w4 = (const float4*)(qw  + (size_t)q*256);
  float4 a, b, c;
  float s = 0.f;
  a = hd[lane]; b = us[lane]; c = t2[lane];
  s += a.x*(b.x+c.x) + a.y*(b.y+c.y) + a.z*(b.z+c.z) + a.w*(b.w+c.w);
  a = hs[lane]; c = t1[lane];
  s += a.x*c.x + a.y*c.y + a.z*c.z + a.w*c.w;
  a = rl[lane]; c = w4[lane];
  s += a.x*c.x + a.y*c.y + a.z*c.z + a.w*c.w;
#pragma unroll
  for (int off=32; off>0; off>>=1) s += __shfl_down(s, off);
  if (lane==0) logits[e] = s + qc[q];
}

// ---------------- segmented softmax over src-node segments ------------------
__global__ void segmax_k(const int* __restrict__ edges, const float* __restrict__ logits,
                         unsigned* __restrict__ menc, int nE)
{
  int e = blockIdx.x*256 + threadIdx.x; if (e >= nE) return;
  atomicMax(menc + edges[(size_t)e*8+6], fenc(logits[e]));
}
__global__ void segexp_k(const int* __restrict__ edges, const float* __restrict__ logits,
                         const unsigned* __restrict__ menc, float* __restrict__ ebuf,
                         float* __restrict__ ssum, int nE)
{
  int e = blockIdx.x*256 + threadIdx.x; if (e >= nE) return;
  int s = edges[(size_t)e*8+6];
  float ex = expf(logits[e] - fdec(menc[s]));
  ebuf[e] = ex;
  atomicAdd(ssum + s, ex);
}
template<int TGT>
__global__ void segsoft_k(const int* __restrict__ edges, const float* __restrict__ ebuf,
                          const float* __restrict__ ssum, float* __restrict__ soft,
                          const float* __restrict__ score, float* __restrict__ target, int nE)
{
  int e = blockIdx.x*256 + threadIdx.x; if (e >= nE) return;
  int s = edges[(size_t)e*8+6];
  float so = ebuf[e] / ssum[s];
  soft[e] = so;
  if (TGT) target[e] = so * score[s];
}

// ---------------- per-query top-64 (bitonic, matches top_k tie order) -------
__global__ __launch_bounds__(256) void topk_k(const float* __restrict__ target,
    const float* __restrict__ soft, const int* __restrict__ edges1,
    float* __restrict__ out0, float* __restrict__ out2, float* __restrict__ out3,
    int* __restrict__ p_src, int* __restrict__ p_dst, float* __restrict__ p_w)
{
  int qb = blockIdx.x, t = threadIdx.x;
  __shared__ float v[256];
  __shared__ int   ix[256];
  v[t] = target[(size_t)qb*256 + t];
  ix[t] = t;
  __syncthreads();
  for (int k=2; k<=256; k<<=1){
    for (int j=k>>1; j>0; j>>=1){
      int ixj = t ^ j;
      if (ixj > t){
        float va=v[t], vb=v[ixj]; int ia=ix[t], ib=ix[ixj];
        bool dir  = ((t & k) == 0);
        bool l_ab = (va > vb) || (va == vb && ia < ib);
        bool sw   = dir ? (!l_ab) : l_ab;
        if (sw){ v[t]=vb; v[ixj]=va; ix[t]=ib; ix[ixj]=ia; }
      }
      __syncthreads();
    }
  }
  if (t < 64){
    int oi = qb*256 + ix[t];
    int o  = qb*64 + t;
    out3[o] = (float)oi;
#pragma unroll
    for (int c2=0;c2<8;++c2) out2[(size_t)o*8 + c2] = (float)edges1[(size_t)oi*8 + c2];
    int s_ = edges1[(size_t)oi*8+6], d_ = edges1[(size_t)oi*8+7];
    p_src[o] = s_; p_dst[o] = d_; p_w[o] = soft[oi];
    atomicAdd(out0 + d_, v[t]);
  }
}

// ---------------- bucketized repr update ------------------------------------
__global__ void bucket_fill(const int* __restrict__ srcarr, int stride, int n,
                            int* __restrict__ counts, int* __restrict__ bucket,
                            int* __restrict__ over, int* __restrict__ n_over)
{
  int e = blockIdx.x*256 + threadIdx.x; if (e >= n) return;
  int s = srcarr[(size_t)e*stride];
  int pos = atomicAdd(counts + s, 1);
  if (pos < BCAP) bucket[(size_t)s*BCAP + pos] = e;
  else { int oi = atomicAdd(n_over, 1); over[oi] = e; }
}

__global__ __launch_bounds__(256) void fused_update(const int* __restrict__ counts,
    const int* __restrict__ bucket, const int* __restrict__ dstarr, int dstride,
    const float* __restrict__ w, const float* __restrict__ Hin, float* __restrict__ Hout)
{
  int lane = threadIdx.x & 63;
  int n = blockIdx.x*4 + (threadIdx.x >> 6);
  if (n >= NN) return;
  int cnt = counts[n];
  float fac = cnt > 0 ? 0.2f : 1.0f;
  float4 h = ((const float4*)(Hin + (size_t)n*256))[lane];
  float4 acc = make_float4(fac*h.x, fac*h.y, fac*h.z, fac*h.w);
  int m = cnt < BCAP ? cnt : BCAP;
  for (int i=0;i<m;++i){
    int e = bucket[(size_t)n*BCAP + i];
    int d = dstarr[(size_t)e*dstride];
    float f = 0.8f * w[e];
    float4 vv = ((const float4*)(Hin + (size_t)d*256))[lane];
    acc.x += f*vv.x; acc.y += f*vv.y; acc.z += f*vv.z; acc.w += f*vv.w;
  }
  ((float4*)(Hout + (size_t)n*256))[lane] = acc;
}

__global__ __launch_bounds__(256) void over_k(const int* __restrict__ over,
    const int* __restrict__ n_over,
    const int* __restrict__ srcarr, int sstride,
    const int* __restrict__ dstarr, int dstride,
    const float* __restrict__ w, const float* __restrict__ Hin, float* __restrict__ Hout)
{
  int lane = threadIdx.x & 63;
  int i = blockIdx.x*4 + (threadIdx.x >> 6);
  if (i >= *n_over) return;
  int e = over[i];
  int s = srcarr[(size_t)e*sstride], d = dstarr[(size_t)e*dstride];
  float f = 0.8f * w[e];
  float4 vv = ((const float4*)(Hin + (size_t)d*256))[lane];
  float* o = Hout + (size_t)s*256 + lane*4;
  atomicAdd(o+0, f*vv.x); atomicAdd(o+1, f*vv.y);
  atomicAdd(o+2, f*vv.z); atomicAdd(o+3, f*vv.w);
}

// ---------------- host launch ------------------------------------------------
extern "C" void kernel_launch(void* const* d_in, const int* in_sizes, int n_in,
                              void* d_out, int out_size, void* d_ws, size_t ws_size,
                              hipStream_t stream)
{
  const float* score = (const float*)d_in[0];
  const float* H0    = (const float*)d_in[1];
  const int*   edges0= (const int*)d_in[2];
  const int*   edges1= (const int*)d_in[3];
  const float* rel0  = (const float*)d_in[4];
  const float* rel1  = (const float*)d_in[5];
  const float* qst   = (const float*)d_in[6];
  const float* qr    = (const float*)d_in[7];
  const float* Wq    = (const float*)d_in[8];
  const float* Wk    = (const float*)d_in[9];
  const float* Wl    = (const float*)d_in[10];
  const float* bl    = (const float*)d_in[11];
  (void)in_sizes; (void)n_in; (void)out_size; (void)ws_size;

  float* out0 = (float*)d_out;
  float* out1 = out0 + NN;
  float* out2 = out1 + (size_t)NN*D;
  float* out3 = out2 + (size_t)NQ*ME*8;

  float* ws     = (float*)d_ws;
  float* Mbuf   = ws;                          // 1,048,576
  float* qt1    = ws + 1048576;
  float* qt2    = ws + 1081344;
  float* qw     = ws + 1114112;
  float* qc     = ws + 1146880;
  float* logits = ws + 1147008;
  float* ebuf   = ws + 1179776;
  float* soft   = ws + 1212544;
  float* target = ws + 1245312;
  unsigned* menc= (unsigned*)(ws + 1278080);
  float* ssum   = ws + 1328080;
  int* p_src    = (int*)(ws + 1378080);
  int* p_dst    = (int*)(ws + 1386272);
  float* p_w    = ws + 1394464;
  float* U      = ws + 1402880;                // 12,800,000
  float* Hnew   = ws + 14202880;               // 12,800,000
  float* SCR    = ws + 27002880;
  int* counts = (int*)SCR;
  int* n_over = (int*)(SCR + 50000);
  int* over   = (int*)(SCR + 50056);
  int* bucket = (int*)(SCR + 100000);          // 1.6M, ends 1.7M
  float* P0   = SCR + 2000000;
  f16* Ah = (f16*)P0;                          // 12.8M f16 = 6.4M floats
  f16* Al = (f16*)(P0 + 6400000);
  f16* Rh = (f16*)(P0 + 12800000);             // 8.39M f16 = 4.19M floats
  f16* Rl = (f16*)(P0 + 16994304);
  f16* mhh_h  = (f16*)(P0 + 21200000);
  f16* mhh_l  = (f16*)(P0 + 21232768);
  f16* wcat_h = (f16*)(P0 + 21265536);
  f16* wcat_l = (f16*)(P0 + 21363840);
  f16* wl_h   = (f16*)(P0 + 21462144);
  f16* wl_l   = (f16*)(P0 + 21494912);         // ends P0+21,527,680 (~202 MB total)
  double* Mpart = (double*)P0;                 // 16.78M floats, dead after reduce_m
  float* Hpre = U;                             // alias: U dead before Hpre written

  hipMemsetAsync(out0, 0, (size_t)NN*4, stream);
  hipMemsetAsync(menc, 0, (size_t)NN*4, stream);
  hipMemsetAsync(ssum, 0, (size_t)NN*4, stream);

  // setup: M (fp64), query tables, B-transposed f16 pairs
  gemm_tn_split<<<dim3(16,16,4), 256, 0, stream>>>(Wq, Wk, Mpart);
  reduce_m<<<4096, 256, 0, stream>>>(Mpart, Mbuf);
  query_tables<<<NQ, 256, 0, stream>>>(Mbuf, qst, qr, qt1, qt2, qw, qc);
  build_bt_mhh<<<256, 256, 0, stream>>>(Mbuf, mhh_h, mhh_l);
  build_bt_wcat<<<768, 256, 0, stream>>>(Mbuf, wcat_h, wcat_l);
  split_f16<<<64, 256, 0, stream>>>(Wl, wl_h, wl_l, 65536);   // BT_wl == Wl

  // ---- call 1: edges1 / rel1 / H0 ----
  split_f16<<<12500, 256, 0, stream>>>(H0, Ah, Al, NN*256);
  hgemm<0><<<dim3(391,2), 256, 0, stream>>>(Ah, Al, NN, mhh_h, mhh_l, U, 256, nullptr);
  slim_logits<<<NE/4, 256, 0, stream>>>(edges1, H0, U, rel1, qt1, qt2, qw, qc, logits);
  split_f16<<<8192, 256, 0, stream>>>(rel1, Rh, Rl, NE*256);
  hgemm_rel<<<dim3(256,6), 256, 0, stream>>>(Rh, Rl, wcat_h, wcat_l, edges1, H0, rel1, logits);

  segmax_k<<<NE/256, 256, 0, stream>>>(edges1, logits, menc, NE);
  segexp_k<<<NE/256, 256, 0, stream>>>(edges1, logits, menc, ebuf, ssum, NE);
  segsoft_k<1><<<NE/256, 256, 0, stream>>>(edges1, ebuf, ssum, soft, score, target, NE);

  topk_k<<<NQ, 256, 0, stream>>>(target, soft, edges1, out0, out2, out3, p_src, p_dst, p_w);

  hipMemsetAsync(counts, 0, (size_t)NN*4, stream);
  hipMemsetAsync(n_over, 0, 4, stream);
  bucket_fill<<<(NQ*ME+255)/256, 256, 0, stream>>>(p_src, 1, NQ*ME, counts, bucket, over, n_over);
  fused_update<<<(NN+3)/4, 256, 0, stream>>>(counts, bucket, p_dst, 1, p_w, H0, Hnew);
  over_k<<<(NQ*ME)/4, 256, 0, stream>>>(over, n_over, p_src, 1, p_dst, 1, p_w, H0, Hnew);

  hipMemsetAsync(menc, 0, (size_t)NN*4, stream);
  hipMemsetAsync(ssum, 0, (size_t)NN*4, stream);

  // ---- call 2: edges0 / rel0 / Hnew ----
  split_f16<<<12500, 256, 0, stream>>>(Hnew, Ah, Al, NN*256);
  hgemm<0><<<dim3(391,2), 256, 0, stream>>>(Ah, Al, NN, mhh_h, mhh_l, U, 256, nullptr);
  slim_logits<<<NE/4, 256, 0, stream>>>(edges0, Hnew, U, rel0, qt1, qt2, qw, qc, logits);
  split_f16<<<8192, 256, 0, stream>>>(rel0, Rh, Rl, NE*256);
  hgemm_rel<<<dim3(256,6), 256, 0, stream>>>(Rh, Rl, wcat_h, wcat_l, edges0, Hnew, rel0, logits);

  segmax_k<<<NE/256, 256, 0, stream>>>(edges0, logits, menc, NE);
  segexp_k<<<NE/256, 256, 0, stream>>>(edges0, logits, menc, ebuf, ssum, NE);
  segsoft_k<0><<<NE/256, 256, 0, stream>>>(edges0, ebuf, ssum, soft, nullptr, nullptr, NE);

  hipMemsetAsync(counts, 0, (size_t)NN*4, stream);
  hipMemsetAsync(n_over, 0, 4, stream);
  bucket_fill<<<NE/256, 256, 0, stream>>>(edges0 + 6, 8, NE, counts, bucket, over, n_over);
  fused_update<<<(NN+3)/4, 256, 0, stream>>>(counts, bucket, edges0 + 7, 8, soft, Hnew, Hpre);
  over_k<<<NE/4, 256, 0, stream>>>(over, n_over, edges0 + 6, 8, edges0 + 7, 8, soft, Hnew, Hpre);

  // final: out1 = leaky_relu(Hpre @ Wl^T + bl)
  split_f16<<<12500, 256, 0, stream>>>(Hpre, Ah, Al, NN*256);
  hgemm<1><<<dim3(391,2), 256, 0, stream>>>(Ah, Al, NN, wl_h, wl_l, out1, 256, bl);
}

// Round 5
// 631.150 us; speedup vs baseline: 2.0882x; 1.1712x over previous
//
#include <hip/hip_runtime.h>

#define NN 50000
#define D 256
#define NQ 128
#define PG 256
#define NE 32768
#define ME 64
#define BCAP 32
#define KDIM 256
#define NKT 8

typedef _Float16 f16;
typedef __attribute__((ext_vector_type(4))) _Float16 f16x4;
typedef __attribute__((ext_vector_type(8))) _Float16 f16x8;
typedef __attribute__((ext_vector_type(4))) float f32x4;

#define MFMA16(a,b,c) __builtin_amdgcn_mfma_f32_16x16x32_f16(a,b,c,0,0,0)

__device__ __forceinline__ unsigned fenc(float f){
  unsigned b = __float_as_uint(f);
  return (b & 0x80000000u) ? ~b : (b | 0x80000000u);
}
__device__ __forceinline__ float fdec(unsigned u){
  unsigned b = (u & 0x80000000u) ? (u & 0x7fffffffu) : ~u;
  return __uint_as_float(b);
}
__device__ __forceinline__ void split8(float4 a, float4 b, f16x8& h, f16x8& l){
  float v[8] = {a.x,a.y,a.z,a.w,b.x,b.y,b.z,b.w};
#pragma unroll
  for (int i=0;i<8;++i){
    _Float16 hh = (_Float16)v[i];
    h[i] = hh;
    l[i] = (_Float16)(v[i] - (float)hh);
  }
}

// ---------- fp16x3 MFMA GEMM: C(f32) = A_f32(M x 256) @ (Bh+Bl)^T -----------
// A is fp32; split into (Ah+Al) in-register during LDS staging (same global
// bytes as pre-split f16 pair). BT is N x 256 row-major pre-split f16.
template<int EPI>
__global__ __launch_bounds__(256) void hgemm(const float* __restrict__ A,
                                             int Mrows,
                                             const f16* __restrict__ Bh, const f16* __restrict__ Bl,
                                             float* __restrict__ C, int ldc,
                                             const float* __restrict__ bias)
{
  __shared__ f16 AsH[128*40], AsL[128*40], BsH[128*40], BsL[128*40];
  const int tid = threadIdx.x;
  const int rb = blockIdx.x*128, cb = blockIdx.y*128;
  const int row = tid >> 1, ko = (tid & 1)*16;
  const bool aok = (rb + row) < Mrows;
  const int lane = tid & 63, wv = tid >> 6;
  const int qrw = (wv & 1)*64, qcw = (wv >> 1)*64;
  const int lm = lane & 15, qd = lane >> 4;

  const float* gA = A + (size_t)(rb+row)*KDIM + ko;
  const f16* gBh = Bh + (size_t)(cb+row)*KDIM + ko;
  const f16* gBl = Bl + (size_t)(cb+row)*KDIM + ko;

  float4 pa0=make_float4(0.f,0.f,0.f,0.f), pa1=pa0, pa2=pa0, pa3=pa0;
  f16x8 pbh0, pbh1, pbl0, pbl1;
  if (aok){ pa0 = *(const float4*)gA;     pa1 = *(const float4*)(gA+4);
            pa2 = *(const float4*)(gA+8); pa3 = *(const float4*)(gA+12); }
  pbh0 = *(const f16x8*)gBh; pbh1 = *(const f16x8*)(gBh+8);
  pbl0 = *(const f16x8*)gBl; pbl1 = *(const f16x8*)(gBl+8);

  f32x4 acc[4][4];
#pragma unroll
  for (int t=0;t<4;++t)
#pragma unroll
    for (int u=0;u<4;++u)
#pragma unroll
      for (int r=0;r<4;++r) acc[t][u][r] = 0.f;

  const int wbase = row*40 + ko;
  for (int kt = 0; kt < NKT; ++kt){
    __syncthreads();
    {
      f16x8 h0,h1,l0,l1;
      split8(pa0,pa1,h0,l0); split8(pa2,pa3,h1,l1);
      *(f16x8*)(AsH + wbase) = h0; *(f16x8*)(AsH + wbase + 8) = h1;
      *(f16x8*)(AsL + wbase) = l0; *(f16x8*)(AsL + wbase + 8) = l1;
      *(f16x8*)(BsH + wbase) = pbh0; *(f16x8*)(BsH + wbase + 8) = pbh1;
      *(f16x8*)(BsL + wbase) = pbl0; *(f16x8*)(BsL + wbase + 8) = pbl1;
    }
    __syncthreads();
    if (kt+1 < NKT){
      const int k0 = (kt+1)*32;
      if (aok){ pa0 = *(const float4*)(gA + k0);     pa1 = *(const float4*)(gA + k0 + 4);
                pa2 = *(const float4*)(gA + k0 + 8); pa3 = *(const float4*)(gA + k0 + 12); }
      pbh0 = *(const f16x8*)(gBh + k0); pbh1 = *(const f16x8*)(gBh + k0 + 8);
      pbl0 = *(const f16x8*)(gBl + k0); pbl1 = *(const f16x8*)(gBl + k0 + 8);
    }
    f16x8 fah[4], fal[4], fbh[4], fbl[4];
#pragma unroll
    for (int t=0;t<4;++t){
      int off = (qrw + t*16 + lm)*40 + qd*8;
      fah[t] = *(const f16x8*)(AsH + off);
      fal[t] = *(const f16x8*)(AsL + off);
    }
#pragma unroll
    for (int u=0;u<4;++u){
      int off = (qcw + u*16 + lm)*40 + qd*8;
      fbh[u] = *(const f16x8*)(BsH + off);
      fbl[u] = *(const f16x8*)(BsL + off);
    }
#pragma unroll
    for (int t=0;t<4;++t)
#pragma unroll
      for (int u=0;u<4;++u){
        acc[t][u] = MFMA16(fah[t], fbh[u], acc[t][u]);
        acc[t][u] = MFMA16(fah[t], fbl[u], acc[t][u]);
        acc[t][u] = MFMA16(fal[t], fbh[u], acc[t][u]);
      }
  }
#pragma unroll
  for (int t=0;t<4;++t){
#pragma unroll
    for (int u=0;u<4;++u){
      int col = cb + qcw + u*16 + lm;
      f32x4 v = acc[t][u];
#pragma unroll
      for (int r=0;r<4;++r){
        int rg = rb + qrw + t*16 + qd*4 + r;
        if (rg < Mrows){
          float x = v[r];
          if (EPI==1){ x += bias[col]; x = x > 0.f ? x : 0.01f*x; }
          C[(size_t)rg*ldc + col] = x;
        }
      }
    }
  }
}

// ---- rel GEMM with fused logits epilogue: partial = sum_j C[e][j]*X[e][j] ---
// A (rel) fp32, split in-register. grid (256, 6): by 0,1 -> X=H[src];
// 2,3 -> H[dst]; 4,5 -> rel[e].
__global__ __launch_bounds__(256) void hgemm_rel(const float* __restrict__ A,
                                                 const f16* __restrict__ Bh, const f16* __restrict__ Bl,
                                                 const int* __restrict__ edges,
                                                 const float* __restrict__ H,
                                                 const float* __restrict__ Rel,
                                                 float* __restrict__ logits)
{
  __shared__ f16 AsH[128*40], AsL[128*40], BsH[128*40], BsL[128*40];
  __shared__ int sIdx[128];
  const int tid = threadIdx.x;
  const int rb = blockIdx.x*128, cb = blockIdx.y*128;
  const int sec = blockIdx.y >> 1;
  const int row = tid >> 1, ko = (tid & 1)*16;
  const int lane = tid & 63, wv = tid >> 6;
  const int qrw = (wv & 1)*64, qcw = (wv >> 1)*64;
  const int lm = lane & 15, qd = lane >> 4;

  if (tid < 128){
    int e = rb + tid;
    sIdx[tid] = (sec==0) ? edges[(size_t)e*8+6] : (sec==1 ? edges[(size_t)e*8+7] : 0);
  }

  const float* gA = A + (size_t)(rb+row)*KDIM + ko;
  const f16* gBh = Bh + (size_t)(cb+row)*KDIM + ko;
  const f16* gBl = Bl + (size_t)(cb+row)*KDIM + ko;

  float4 pa0 = *(const float4*)gA,     pa1 = *(const float4*)(gA+4);
  float4 pa2 = *(const float4*)(gA+8), pa3 = *(const float4*)(gA+12);
  f16x8 pbh0 = *(const f16x8*)gBh, pbh1 = *(const f16x8*)(gBh+8);
  f16x8 pbl0 = *(const f16x8*)gBl, pbl1 = *(const f16x8*)(gBl+8);

  f32x4 acc[4][4];
#pragma unroll
  for (int t=0;t<4;++t)
#pragma unroll
    for (int u=0;u<4;++u)
#pragma unroll
      for (int r=0;r<4;++r) acc[t][u][r] = 0.f;

  const int wbase = row*40 + ko;
  for (int kt = 0; kt < NKT; ++kt){
    __syncthreads();
    {
      f16x8 h0,h1,l0,l1;
      split8(pa0,pa1,h0,l0); split8(pa2,pa3,h1,l1);
      *(f16x8*)(AsH + wbase) = h0; *(f16x8*)(AsH + wbase + 8) = h1;
      *(f16x8*)(AsL + wbase) = l0; *(f16x8*)(AsL + wbase + 8) = l1;
      *(f16x8*)(BsH + wbase) = pbh0; *(f16x8*)(BsH + wbase + 8) = pbh1;
      *(f16x8*)(BsL + wbase) = pbl0; *(f16x8*)(BsL + wbase + 8) = pbl1;
    }
    __syncthreads();
    if (kt+1 < NKT){
      const int k0 = (kt+1)*32;
      pa0 = *(const float4*)(gA + k0);     pa1 = *(const float4*)(gA + k0 + 4);
      pa2 = *(const float4*)(gA + k0 + 8); pa3 = *(const float4*)(gA + k0 + 12);
      pbh0 = *(const f16x8*)(gBh + k0); pbh1 = *(const f16x8*)(gBh + k0 + 8);
      pbl0 = *(const f16x8*)(gBl + k0); pbl1 = *(const f16x8*)(gBl + k0 + 8);
    }
    f16x8 fah[4], fal[4], fbh[4], fbl[4];
#pragma unroll
    for (int t=0;t<4;++t){
      int off = (qrw + t*16 + lm)*40 + qd*8;
      fah[t] = *(const f16x8*)(AsH + off);
      fal[t] = *(const f16x8*)(AsL + off);
    }
#pragma unroll
    for (int u=0;u<4;++u){
      int off = (qcw + u*16 + lm)*40 + qd*8;
      fbh[u] = *(const f16x8*)(BsH + off);
      fbl[u] = *(const f16x8*)(BsL + off);
    }
#pragma unroll
    for (int t=0;t<4;++t)
#pragma unroll
      for (int u=0;u<4;++u){
        acc[t][u] = MFMA16(fah[t], fbh[u], acc[t][u]);
        acc[t][u] = MFMA16(fah[t], fbl[u], acc[t][u]);
        acc[t][u] = MFMA16(fal[t], fbh[u], acc[t][u]);
      }
  }
  const int cbase = ((blockIdx.y & 1)*128) + qcw + lm;
#pragma unroll
  for (int t=0;t<4;++t){
#pragma unroll
    for (int r=0;r<4;++r){
      int lrow = qrw + t*16 + qd*4 + r;
      int e = rb + lrow;
      const float* xb = (sec==2) ? (Rel + (size_t)e*256)
                                 : (H + (size_t)sIdx[lrow]*256);
      float p = acc[t][0][r]*xb[cbase]
              + acc[t][1][r]*xb[cbase+16]
              + acc[t][2][r]*xb[cbase+32]
              + acc[t][3][r]*xb[cbase+48];
      p += __shfl_xor(p, 1); p += __shfl_xor(p, 2);
      p += __shfl_xor(p, 4); p += __shfl_xor(p, 8);
      if (lm == 0) atomicAdd(logits + e, p);
    }
  }
}

// ---------------- fp16 split helper (small matrices only) -------------------
__global__ void split_f16(const float* __restrict__ X, f16* __restrict__ Xh,
                          f16* __restrict__ Xl, int n)
{
  int i = (blockIdx.x*256 + threadIdx.x)*4;
  if (i >= n) return;
  float4 v = *(const float4*)(X+i);
  f16x4 h, l;
  h[0]=(_Float16)v.x; h[1]=(_Float16)v.y; h[2]=(_Float16)v.z; h[3]=(_Float16)v.w;
  l[0]=(_Float16)(v.x-(float)h[0]); l[1]=(_Float16)(v.y-(float)h[1]);
  l[2]=(_Float16)(v.z-(float)h[2]); l[3]=(_Float16)(v.w-(float)h[3]);
  *(f16x4*)(Xh+i)=h; *(f16x4*)(Xl+i)=l;
}

__global__ void build_bt_mhh(const float* __restrict__ M, f16* __restrict__ Bh, f16* __restrict__ Bl)
{
  int idx = blockIdx.x*256 + threadIdx.x;   // 65536: BT[n][k] = M_hh[k][n]
  int n = idx >> 8, k = idx & 255;
  float v = M[(size_t)k*1024 + n];
  _Float16 h = (_Float16)v;
  Bh[idx] = h; Bl[idx] = (_Float16)(v - (float)h);
}

__global__ void build_bt_wcat(const float* __restrict__ M, f16* __restrict__ Bh, f16* __restrict__ Bl)
{
  int idx = blockIdx.x*256 + threadIdx.x;   // 196608: BT[j][k] = Wcat[k][j]
  int j = idx >> 8, k = idx & 255;
  float v;
  if (j < 256)      v = M[(size_t)j*1024 + 256 + k];            // a1 = M_hr^T
  else if (j < 512) v = M[(size_t)(256+k)*1024 + (j-256)];      // a2 = M_rh
  else              v = M[(size_t)(256 + j-512)*1024 + 256 + k];// a3 = M_rr^T
  _Float16 h = (_Float16)v;
  Bh[idx] = h; Bl[idx] = (_Float16)(v - (float)h);
}

// ------- M = Wq^T @ Wk (1024x1024), fp64 accumulate, split-K x8 -------------
__global__ __launch_bounds__(256) void gemm_tn_split(const float* __restrict__ A,
                                                     const float* __restrict__ B,
                                                     double* __restrict__ Cpart)
{
  __shared__ float As[16][68];
  __shared__ float Bs[16][68];
  const int tid = threadIdx.x;
  const int rb = blockIdx.x * 64, cb = blockIdx.y * 64;
  const int z  = blockIdx.z;
  const int ty = tid >> 4, tx = tid & 15;
  const int aj = tid >> 4, akk = (tid & 15) << 2;
  double acc[4][4] = {};
  const int jbeg = z * 128, jend = jbeg + 128;
  for (int j0 = jbeg; j0 < jend; j0 += 16) {
    float4 av = *(const float4*)(A + (size_t)(j0+aj)*1024 + rb + akk);
    As[aj][akk+0]=av.x; As[aj][akk+1]=av.y; As[aj][akk+2]=av.z; As[aj][akk+3]=av.w;
    float4 bv = *(const float4*)(B + (size_t)(j0+aj)*1024 + cb + akk);
    Bs[aj][akk+0]=bv.x; Bs[aj][akk+1]=bv.y; Bs[aj][akk+2]=bv.z; Bs[aj][akk+3]=bv.w;
    __syncthreads();
#pragma unroll
    for (int jj=0; jj<16; ++jj){
      float a0=As[jj][ty*4+0],a1=As[jj][ty*4+1],a2=As[jj][ty*4+2],a3=As[jj][ty*4+3];
      float b0=Bs[jj][tx*4+0],b1=Bs[jj][tx*4+1],b2=Bs[jj][tx*4+2],b3=Bs[jj][tx*4+3];
      acc[0][0]+=(double)a0*b0; acc[0][1]+=(double)a0*b1; acc[0][2]+=(double)a0*b2; acc[0][3]+=(double)a0*b3;
      acc[1][0]+=(double)a1*b0; acc[1][1]+=(double)a1*b1; acc[1][2]+=(double)a1*b2; acc[1][3]+=(double)a1*b3;
      acc[2][0]+=(double)a2*b0; acc[2][1]+=(double)a2*b1; acc[2][2]+=(double)a2*b2; acc[2][3]+=(double)a2*b3;
      acc[3][0]+=(double)a3*b0; acc[3][1]+=(double)a3*b1; acc[3][2]+=(double)a3*b2; acc[3][3]+=(double)a3*b3;
    }
    __syncthreads();
  }
  double* Cz = Cpart + (size_t)z * 1048576;
#pragma unroll
  for (int i=0;i<4;++i)
#pragma unroll
    for (int j=0;j<4;++j)
      Cz[(size_t)(rb+ty*4+i)*1024 + cb+tx*4+j] = acc[i][j];
}

__global__ void reduce_m(const double* __restrict__ P, float* __restrict__ Mout)
{
  int i = blockIdx.x*256 + threadIdx.x;
  double s = 0.0;
#pragma unroll
  for (int z=0;z<8;++z) s += P[(size_t)i + (size_t)z*1048576];
  Mout[i] = (float)s;
}

// ---------------- query tables as GEMM --------------------------------------
__global__ void build_g(const float* __restrict__ qst, const float* __restrict__ qr,
                        float* __restrict__ G)
{
  int idx = blockIdx.x*256 + threadIdx.x;   // 65536
  int q = idx >> 9, k = idx & 511;
  G[idx] = (k < 256) ? qst[(size_t)q*256 + k] : qr[(size_t)q*256 + k - 256];
}

// Bq (512 x 1280): cols [qt1-proj | qt2-proj | qw-proj | M_gg]
__global__ void build_bq(const float* __restrict__ M, float* __restrict__ Bq)
{
  int idx = blockIdx.x*256 + threadIdx.x;   // 655360
  int k = idx / 1280, t = idx - k*1280;
  float v;
  if (t < 256)      v = M[(size_t)t*1024 + 512 + k];
  else if (t < 512) v = M[(size_t)(512+k)*1024 + (t-256)];
  else if (t < 768) v = M[(size_t)(256+(t-512))*1024 + 512 + k]
                      + M[(size_t)(512+k)*1024 + 256 + (t-512)];
  else              v = M[(size_t)(512+k)*1024 + 512 + (t-768)];
  Bq[idx] = v;
}

// fp32 GEMM 64x64 tile, conflict-aware, prefetch (for the tiny qtab product)
__global__ __launch_bounds__(256) void gemm64(const float* __restrict__ A, int lda,
                                              const float* __restrict__ B, int ldb,
                                              float* __restrict__ C, int ldc,
                                              int Mrows, int Kdim)
{
  __shared__ float As[16][68];
  __shared__ float Bs[16][68];
  const int tid = threadIdx.x;
  const int rb = blockIdx.x*64, cb = blockIdx.y*64;
  const int tx = tid & 15, ty = tid >> 4;
  const int a_r = tid >> 2, a_k = (tid & 3)*4;
  const int b_c = tid & 63, b_r0 = (tid >> 6)*4;
  const bool aok = (rb + a_r) < Mrows;
  float4 pa = make_float4(0.f,0.f,0.f,0.f);
  float pb[4];
  if (aok) pa = *(const float4*)(A + (size_t)(rb+a_r)*lda + a_k);
#pragma unroll
  for (int j=0;j<4;++j) pb[j] = B[(size_t)(b_r0+j)*ldb + cb + b_c];
  float acc[4][4] = {};
  const int NK = Kdim >> 4;
  for (int t0=0; t0<NK; ++t0){
    __syncthreads();
    As[a_k+0][a_r]=pa.x; As[a_k+1][a_r]=pa.y; As[a_k+2][a_r]=pa.z; As[a_k+3][a_r]=pa.w;
#pragma unroll
    for (int j=0;j<4;++j) Bs[b_r0+j][b_c] = pb[j];
    __syncthreads();
    if (t0+1 < NK){
      int k0 = (t0+1) << 4;
      if (aok) pa = *(const float4*)(A + (size_t)(rb+a_r)*lda + k0 + a_k);
#pragma unroll
      for (int j=0;j<4;++j) pb[j] = B[(size_t)(k0+b_r0+j)*ldb + cb + b_c];
    }
#pragma unroll
    for (int kk=0;kk<16;++kk){
      float a[4], b[4];
      *(float4*)&a[0] = *(const float4*)&As[kk][ty*4];
#pragma unroll
      for (int j=0;j<4;++j) b[j] = Bs[kk][tx + 16*j];
#pragma unroll
      for (int i=0;i<4;++i)
#pragma unroll
        for (int j=0;j<4;++j) acc[i][j] += a[i]*b[j];
    }
  }
#pragma unroll
  for (int i=0;i<4;++i){
    int r = rb + ty*4 + i;
    if (r < Mrows)
#pragma unroll
      for (int j=0;j<4;++j)
        C[(size_t)r*ldc + cb + tx + 16*j] = acc[i][j];
  }
}

__global__ __launch_bounds__(256) void qc_dot(const float* __restrict__ Ccat,
    const float* __restrict__ qst, const float* __restrict__ qr, float* __restrict__ qc)
{
  __shared__ float red[256];
  int q = blockIdx.x, t = threadIdx.x;
  float a = Ccat[(size_t)q*1280 + 768 + t]  * qst[(size_t)q*256 + t]
          + Ccat[(size_t)q*1280 + 1024 + t] * qr [(size_t)q*256 + t];
  red[t] = a;
  __syncthreads();
  for (int s=128; s>0; s>>=1){
    if (t < s) red[t] += red[t+s];
    __syncthreads();
  }
  if (t==0) qc[q] = red[0];
}

// ---------------- slim per-edge logits (non-g terms) ------------------------
__global__ __launch_bounds__(256) void slim_logits(const int* __restrict__ edges,
    const float* __restrict__ H, const float* __restrict__ U,
    const float* __restrict__ Rel,
    const float* __restrict__ Ct, const float* __restrict__ qc,
    float* __restrict__ logits)
{
  int lane = threadIdx.x & 63;
  int e = blockIdx.x*4 + (threadIdx.x >> 6);
  int q   = edges[(size_t)e*8 + 0];
  int src = edges[(size_t)e*8 + 6];
  int dst = edges[(size_t)e*8 + 7];
  const float4* hs = (const float4*)(H   + (size_t)src*256);
  const float4* hd = (const float4*)(H   + (size_t)dst*256);
  const float4* us = (const float4*)(U   + (size_t)src*256);
  const float4* rl = (const float4*)(Rel + (size_t)e*256);
  const float4* t1 = (const float4*)(Ct + (size_t)q*1280);
  const float4* t2 = (const float4*)(Ct + (size_t)q*1280 + 256);
  const float4* w4 = (const float4*)(Ct + (size_t)q*1280 + 512);
  float4 a, b, c;
  float s = 0.f;
  a = hd[lane]; b = us[lane]; c = t2[lane];
  s += a.x*(b.x+c.x) + a.y*(b.y+c.y) + a.z*(b.z+c.z) + a.w*(b.w+c.w);
  a = hs[lane]; c = t1[lane];
  s += a.x*c.x + a.y*c.y + a.z*c.z + a.w*c.w;
  a = rl[lane]; c = w4[lane];
  s += a.x*c.x + a.y*c.y + a.z*c.z + a.w*c.w;
#pragma unroll
  for (int off=32; off>0; off>>=1) s += __shfl_down(s, off);
  if (lane==0) logits[e] = s + qc[q];
}

// ---------------- segmented softmax over src-node segments ------------------
__global__ void segmax_k(const int* __restrict__ edges, const float* __restrict__ logits,
                         unsigned* __restrict__ menc, int nE)
{
  int e = blockIdx.x*256 + threadIdx.x; if (e >= nE) return;
  atomicMax(menc + edges[(size_t)e*8+6], fenc(logits[e]));
}
__global__ void segexp_k(const int* __restrict__ edges, const float* __restrict__ logits,
                         const unsigned* __restrict__ menc, float* __restrict__ ebuf,
                         float* __restrict__ ssum, int nE)
{
  int e = blockIdx.x*256 + threadIdx.x; if (e >= nE) return;
  int s = edges[(size_t)e*8+6];
  float ex = expf(logits[e] - fdec(menc[s]));
  ebuf[e] = ex;
  atomicAdd(ssum + s, ex);
}
template<int TGT>
__global__ void segsoft_k(const int* __restrict__ edges, const float* __restrict__ ebuf,
                          const float* __restrict__ ssum, float* __restrict__ soft,
                          const float* __restrict__ score, float* __restrict__ target, int nE)
{
  int e = blockIdx.x*256 + threadIdx.x; if (e >= nE) return;
  int s = edges[(size_t)e*8+6];
  float so = ebuf[e] / ssum[s];
  soft[e] = so;
  if (TGT) target[e] = so * score[s];
}

// ---------------- per-query top-64 (bitonic, matches top_k tie order) -------
__global__ __launch_bounds__(256) void topk_k(const float* __restrict__ target,
    const float* __restrict__ soft, const int* __restrict__ edges1,
    float* __restrict__ out0, float* __restrict__ out2, float* __restrict__ out3,
    int* __restrict__ p_src, int* __restrict__ p_dst, float* __restrict__ p_w)
{
  int qb = blockIdx.x, t = threadIdx.x;
  __shared__ float v[256];
  __shared__ int   ix[256];
  v[t] = target[(size_t)qb*256 + t];
  ix[t] = t;
  __syncthreads();
  for (int k=2; k<=256; k<<=1){
    for (int j=k>>1; j>0; j>>=1){
      int ixj = t ^ j;
      if (ixj > t){
        float va=v[t], vb=v[ixj]; int ia=ix[t], ib=ix[ixj];
        bool dir  = ((t & k) == 0);
        bool l_ab = (va > vb) || (va == vb && ia < ib);
        bool sw   = dir ? (!l_ab) : l_ab;
        if (sw){ v[t]=vb; v[ixj]=va; ix[t]=ib; ix[ixj]=ia; }
      }
      __syncthreads();
    }
  }
  if (t < 64){
    int oi = qb*256 + ix[t];
    int o  = qb*64 + t;
    out3[o] = (float)oi;
#pragma unroll
    for (int c2=0;c2<8;++c2) out2[(size_t)o*8 + c2] = (float)edges1[(size_t)oi*8 + c2];
    int s_ = edges1[(size_t)oi*8+6], d_ = edges1[(size_t)oi*8+7];
    p_src[o] = s_; p_dst[o] = d_; p_w[o] = soft[oi];
    atomicAdd(out0 + d_, v[t]);
  }
}

// ---------------- bucketized repr update ------------------------------------
__global__ void bucket_fill(const int* __restrict__ srcarr, int stride, int n,
                            int* __restrict__ counts, int* __restrict__ bucket,
                            int* __restrict__ over, int* __restrict__ n_over)
{
  int e = blockIdx.x*256 + threadIdx.x; if (e >= n) return;
  int s = srcarr[(size_t)e*stride];
  int pos = atomicAdd(counts + s, 1);
  if (pos < BCAP) bucket[(size_t)s*BCAP + pos] = e;
  else { int oi = atomicAdd(n_over, 1); over[oi] = e; }
}

__global__ __launch_bounds__(256) void fused_update(const int* __restrict__ counts,
    const int* __restrict__ bucket, const int* __restrict__ dstarr, int dstride,
    const float* __restrict__ w, const float* __restrict__ Hin, float* __restrict__ Hout)
{
  int lane = threadIdx.x & 63;
  int n = blockIdx.x*4 + (threadIdx.x >> 6);
  if (n >= NN) return;
  int cnt = counts[n];
  float fac = cnt > 0 ? 0.2f : 1.0f;
  float4 h = ((const float4*)(Hin + (size_t)n*256))[lane];
  float4 acc = make_float4(fac*h.x, fac*h.y, fac*h.z, fac*h.w);
  int m = cnt < BCAP ? cnt : BCAP;
  for (int i=0;i<m;++i){
    int e = bucket[(size_t)n*BCAP + i];
    int d = dstarr[(size_t)e*dstride];
    float f = 0.8f * w[e];
    float4 vv = ((const float4*)(Hin + (size_t)d*256))[lane];
    acc.x += f*vv.x; acc.y += f*vv.y; acc.z += f*vv.z; acc.w += f*vv.w;
  }
  ((float4*)(Hout + (size_t)n*256))[lane] = acc;
}

__global__ __launch_bounds__(256) void over_k(const int* __restrict__ over,
    const int* __restrict__ n_over,
    const int* __restrict__ srcarr, int sstride,
    const int* __restrict__ dstarr, int dstride,
    const float* __restrict__ w, const float* __restrict__ Hin, float* __restrict__ Hout)
{
  int lane = threadIdx.x & 63;
  int i = blockIdx.x*4 + (threadIdx.x >> 6);
  if (i >= *n_over) return;
  int e = over[i];
  int s = srcarr[(size_t)e*sstride], d = dstarr[(size_t)e*dstride];
  float f = 0.8f * w[e];
  float4 vv = ((const float4*)(Hin + (size_t)d*256))[lane];
  float* o = Hout + (size_t)s*256 + lane*4;
  atomicAdd(o+0, f*vv.x); atomicAdd(o+1, f*vv.y);
  atomicAdd(o+2, f*vv.z); atomicAdd(o+3, f*vv.w);
}

// ---------------- host launch ------------------------------------------------
extern "C" void kernel_launch(void* const* d_in, const int* in_sizes, int n_in,
                              void* d_out, int out_size, void* d_ws, size_t ws_size,
                              hipStream_t stream)
{
  const float* score = (const float*)d_in[0];
  const float* H0    = (const float*)d_in[1];
  const int*   edges0= (const int*)d_in[2];
  const int*   edges1= (const int*)d_in[3];
  const float* rel0  = (const float*)d_in[4];
  const float* rel1  = (const float*)d_in[5];
  const float* qst   = (const float*)d_in[6];
  const float* qr    = (const float*)d_in[7];
  const float* Wq    = (const float*)d_in[8];
  const float* Wk    = (const float*)d_in[9];
  const float* Wl    = (const float*)d_in[10];
  const float* bl    = (const float*)d_in[11];
  (void)in_sizes; (void)n_in; (void)out_size; (void)ws_size;

  float* out0 = (float*)d_out;
  float* out1 = out0 + NN;
  float* out2 = out1 + (size_t)NN*D;
  float* out3 = out2 + (size_t)NQ*ME*8;

  float* ws     = (float*)d_ws;
  float* Mbuf   = ws;                          // 1,048,576
  float* Ccat   = ws + 1048576;                // 128x1280 = 163,840
  float* qcv    = ws + 1212416;                // 128
  float* G      = ws + 1212544;                // 65,536
  float* logits = ws + 1278080;                // 32,768
  float* ebuf   = ws + 1310848;
  float* soft   = ws + 1343616;
  float* target = ws + 1376384;
  unsigned* menc= (unsigned*)(ws + 1409152);   // 50,000
  float* ssum   = ws + 1459152;                // 50,000
  int* p_src    = (int*)(ws + 1509152);        // 8,192
  int* p_dst    = (int*)(ws + 1517344);
  float* p_w    = ws + 1525536;                // ends 1,533,728
  float* Bq     = ws + 1533728;                // 512x1280 = 655,360 -> 2,189,088
  float* U      = ws + 2189088;                // 12,800,000 -> 14,989,088
  float* Hnew   = ws + 14989088;               // 12,800,000 -> 27,789,088
  float* SCR    = ws + 27789088;
  int* counts = (int*)SCR;                     // 50,000
  int* n_over = (int*)(SCR + 50000);           // 1
  int* over   = (int*)(SCR + 50056);           // 32,768
  int* bucket = (int*)(SCR + 100000);          // 1,600,000 -> SCR+1,700,000
  float* P0   = SCR + 2000000;                 // = ws + 29,789,088
  double* Mpart = (double*)P0;                 // 8M doubles = 16M floats (dead after reduce_m)
  f16* mhh_h  = (f16*)P0;                      // aliases Mpart (built after reduce_m)
  f16* mhh_l  = (f16*)(P0 + 32768);
  f16* wcat_h = (f16*)(P0 + 65536);
  f16* wcat_l = (f16*)(P0 + 163840);
  f16* wl_h   = (f16*)(P0 + 262144);
  f16* wl_l   = (f16*)(P0 + 294912);           // ends P0+327,680 (~186 MB total ws)
  float* Hpre = U;                             // alias: U dead before Hpre written

  hipMemsetAsync(out0, 0, (size_t)NN*4, stream);
  hipMemsetAsync(menc, 0, (size_t)NN*4, stream);
  hipMemsetAsync(ssum, 0, (size_t)NN*4, stream);

  // setup: M (fp64 split-K x8), query tables via GEMM, f16 B builders
  gemm_tn_split<<<dim3(16,16,8), 256, 0, stream>>>(Wq, Wk, Mpart);
  reduce_m<<<4096, 256, 0, stream>>>(Mpart, Mbuf);
  build_g<<<256, 256, 0, stream>>>(qst, qr, G);
  build_bq<<<2560, 256, 0, stream>>>(Mbuf, Bq);
  gemm64<<<dim3(2,20), 256, 0, stream>>>(G, 512, Bq, 1280, Ccat, 1280, NQ, 512);
  qc_dot<<<NQ, 256, 0, stream>>>(Ccat, qst, qr, qcv);
  build_bt_mhh<<<256, 256, 0, stream>>>(Mbuf, mhh_h, mhh_l);
  build_bt_wcat<<<768, 256, 0, stream>>>(Mbuf, wcat_h, wcat_l);
  split_f16<<<64, 256, 0, stream>>>(Wl, wl_h, wl_l, 65536);   // BT_wl == Wl

  // ---- call 1: edges1 / rel1 / H0 ----
  hgemm<0><<<dim3(391,2), 256, 0, stream>>>(H0, NN, mhh_h, mhh_l, U, 256, nullptr);
  slim_logits<<<NE/4, 256, 0, stream>>>(edges1, H0, U, rel1, Ccat, qcv, logits);
  hgemm_rel<<<dim3(256,6), 256, 0, stream>>>(rel1, wcat_h, wcat_l, edges1, H0, rel1, logits);

  segmax_k<<<NE/256, 256, 0, stream>>>(edges1, logits, menc, NE);
  segexp_k<<<NE/256, 256, 0, stream>>>(edges1, logits, menc, ebuf, ssum, NE);
  segsoft_k<1><<<NE/256, 256, 0, stream>>>(edges1, ebuf, ssum, soft, score, target, NE);

  topk_k<<<NQ, 256, 0, stream>>>(target, soft, edges1, out0, out2, out3, p_src, p_dst, p_w);

  hipMemsetAsync(counts, 0, (size_t)NN*4, stream);
  hipMemsetAsync(n_over, 0, 4, stream);
  bucket_fill<<<(NQ*ME+255)/256, 256, 0, stream>>>(p_src, 1, NQ*ME, counts, bucket, over, n_over);
  fused_update<<<(NN+3)/4, 256, 0, stream>>>(counts, bucket, p_dst, 1, p_w, H0, Hnew);
  over_k<<<(NQ*ME)/4, 256, 0, stream>>>(over, n_over, p_src, 1, p_dst, 1, p_w, H0, Hnew);

  hipMemsetAsync(menc, 0, (size_t)NN*4, stream);
  hipMemsetAsync(ssum, 0, (size_t)NN*4, stream);

  // ---- call 2: edges0 / rel0 / Hnew ----
  hgemm<0><<<dim3(391,2), 256, 0, stream>>>(Hnew, NN, mhh_h, mhh_l, U, 256, nullptr);
  slim_logits<<<NE/4, 256, 0, stream>>>(edges0, Hnew, U, rel0, Ccat, qcv, logits);
  hgemm_rel<<<dim3(256,6), 256, 0, stream>>>(rel0, wcat_h, wcat_l, edges0, Hnew, rel0, logits);

  segmax_k<<<NE/256, 256, 0, stream>>>(edges0, logits, menc, NE);
  segexp_k<<<NE/256, 256, 0, stream>>>(edges0, logits, menc, ebuf, ssum, NE);
  segsoft_k<0><<<NE/256, 256, 0, stream>>>(edges0, ebuf, ssum, soft, nullptr, nullptr, NE);

  hipMemsetAsync(counts, 0, (size_t)NN*4, stream);
  hipMemsetAsync(n_over, 0, 4, stream);
  bucket_fill<<<NE/256, 256, 0, stream>>>(edges0 + 6, 8, NE, counts, bucket, over, n_over);
  fused_update<<<(NN+3)/4, 256, 0, stream>>>(counts, bucket, edges0 + 7, 8, soft, Hnew, Hpre);
  over_k<<<NE/4, 256, 0, stream>>>(over, n_over, edges0 + 6, 8, edges0 + 7, 8, soft, Hnew, Hpre);

  // final: out1 = leaky_relu(Hpre @ Wl^T + bl)
  hgemm<1><<<dim3(391,2), 256, 0, stream>>>(Hpre, NN, wl_h, wl_l, out1, 256, bl);
}